// Round 1
// baseline (379.562 us; speedup 1.0000x reference)
//
#include <hip/hip_runtime.h>
#include <hip/hip_bf16.h>
#include <math.h>

// Problem constants
#define BB 256
#define DD 512
#define LL 196
#define NN 1024
#define MM 512
#define KK 10000

// ---- workspace layout (float offsets) ----
#define OFF_PE    ((size_t)0)               // B*4*L       = 200704
#define OFF_BETA  ((size_t)200704)          // B           = 256
#define OFF_Z     ((size_t)200960)          // B*D         = 131072
#define OFF_EMBP  ((size_t)332032)          // 8*B*M       = 1048576
#define OFF_X     ((size_t)1380608)         // B*2048      = 524288
#define OFF_IHP   ((size_t)1904896)         // 2*B*4096    = 2097152
#define OFF_HHP   ((size_t)4002048)         // B*4096      = 1048576
#define OFF_LHP   ((size_t)5050624)         // 4*B*M       = 524288
#define OFF_LZP   ((size_t)5574912)         // 2*B*M       = 262144
#define OFF_DEEP  ((size_t)5837056)         // B*M         = 131072
// total = 5968128 floats = 23.9 MB

// ---- output layout (float offsets) ----
#define OUT_PY 0
#define OUT_HN ((size_t)2560000)
#define OUT_CN ((size_t)2822144)
#define OUT_AL ((size_t)3084288)

// e_partial: pe[b][ch][l] = sum_{d in chunk ch} a_i[b,d,l] * w_a[d]
__global__ __launch_bounds__(256) void att_e_partial(
    const float* __restrict__ a_i, const float* __restrict__ f_att_w,
    float* __restrict__ pe)
{
    const int b = blockIdx.x, ch = blockIdx.y;
    const int l = threadIdx.x;
    if (l >= LL) return;
    const float* ap = a_i + ((size_t)b * DD + ch * 128) * LL + l;
    const float* wp = f_att_w + ch * 128;
    float s = 0.f;
#pragma unroll 8
    for (int d = 0; d < 128; ++d) s += ap[(size_t)d * LL] * wp[d];
    pe[((size_t)b * 4 + ch) * LL + l] = s;
}

// per-b: hdot = h.w_h, gdot = h.gate_w, e = sum(pe)+hdot+bias, softmax -> alpha; beta = sigmoid(gdot+gb)
__global__ __launch_bounds__(256) void att_softmax(
    const float* __restrict__ pe, const float* __restrict__ h,
    const float* __restrict__ f_att_w, const float* __restrict__ f_att_b,
    const float* __restrict__ gate_w, const float* __restrict__ gate_b,
    float* __restrict__ alpha_out, float* __restrict__ beta)
{
    const int b = blockIdx.x;
    const int t = threadIdx.x;
    __shared__ float red[256];
    __shared__ float red2[256];

    const float4 h4 = *(const float4*)(h + (size_t)b * NN + t * 4);
    const float4 w4 = *(const float4*)(f_att_w + DD + t * 4);
    const float4 g4 = *(const float4*)(gate_w + t * 4);
    float hd = h4.x * w4.x + h4.y * w4.y + h4.z * w4.z + h4.w * w4.w;
    float gd = h4.x * g4.x + h4.y * g4.y + h4.z * g4.z + h4.w * g4.w;
    red[t] = hd; red2[t] = gd;
    __syncthreads();
    for (int s = 128; s > 0; s >>= 1) {
        if (t < s) { red[t] += red[t + s]; red2[t] += red2[t + s]; }
        __syncthreads();
    }
    const float hdot = red[0];
    const float gdot = red2[0];
    __syncthreads();

    float e = -1e30f;
    if (t < LL) {
        const float* p = pe + (size_t)b * 4 * LL + t;
        e = p[0] + p[LL] + p[2 * LL] + p[3 * LL] + hdot + f_att_b[0];
    }
    red[t] = e;
    __syncthreads();
    for (int s = 128; s > 0; s >>= 1) {
        if (t < s) red[t] = fmaxf(red[t], red[t + s]);
        __syncthreads();
    }
    const float mx = red[0];
    __syncthreads();
    const float ex = (t < LL) ? expf(e - mx) : 0.f;
    red[t] = ex;
    __syncthreads();
    for (int s = 128; s > 0; s >>= 1) {
        if (t < s) red[t] += red[t + s];
        __syncthreads();
    }
    const float inv = 1.f / red[0];
    if (t < LL) alpha_out[(size_t)b * LL + t] = ex * inv;
    if (t == 0) beta[b] = 1.f / (1.f + expf(-(gdot + gate_b[0])));
}

// z[b,d] = beta[b] * sum_l alpha[b,l] * a_i[b,d,l] ; one wave per d
__global__ __launch_bounds__(256) void att_z(
    const float* __restrict__ a_i, const float* __restrict__ alpha,
    const float* __restrict__ beta, float* __restrict__ z)
{
    const int b = blockIdx.x;
    const int wave = threadIdx.x >> 6, lane = threadIdx.x & 63;
    const int d = blockIdx.y * 4 + wave;
    const float* ap = a_i + ((size_t)b * DD + d) * LL;
    const float* alp = alpha + (size_t)b * LL;
    float s = 0.f;
    for (int l = lane; l < LL; l += 64) s += ap[l] * alp[l];
#pragma unroll
    for (int off = 32; off > 0; off >>= 1) s += __shfl_down(s, off, 64);
    if (lane == 0) z[(size_t)b * DD + d] = beta[b] * s;
}

// Generic TN GEMM: C[r,c] = sum_k A[r, k] * Bw[c, k]   (both k-contiguous)
// 64x64 tile, BK=16, 256 threads, 4x4 per-thread. Split-K via blockIdx.z
// writing to partial buffer C + z*M*ldc. M = gridDim.x*64 (always 256 here).
__global__ __launch_bounds__(256) void gemm_tn(
    const float* __restrict__ A, int lda,
    const float* __restrict__ Bw, int ldb,
    float* __restrict__ C, int ldc,
    int Ncols, int Ktot, int ktPerSplit,
    const float* __restrict__ bias)
{
    __shared__ float As[16][68];
    __shared__ float Bs[16][68];
    const int t = threadIdx.x;
    const int row0 = blockIdx.x * 64;
    const int col0 = blockIdx.y * 64;
    const int ktTot = Ktot >> 4;
    const int kt0 = blockIdx.z * ktPerSplit;
    const int kt1 = min(ktTot, kt0 + ktPerSplit);
    const int lr = t >> 2;           // 0..63
    const int lc = (t & 3) << 2;     // 0,4,8,12
    const int tx = t & 15, ty = t >> 4;
    float acc[4][4] = {{0.f, 0.f, 0.f, 0.f}, {0.f, 0.f, 0.f, 0.f},
                       {0.f, 0.f, 0.f, 0.f}, {0.f, 0.f, 0.f, 0.f}};
    const int brow = col0 + lr;
    const float* aBase = A + (size_t)(row0 + lr) * lda + lc;
    const float* bBase = (brow < Ncols) ? (Bw + (size_t)brow * ldb + lc) : nullptr;

    for (int kt = kt0; kt < kt1; ++kt) {
        const int k = kt << 4;
        const float4 av = *(const float4*)(aBase + k);
        float4 bv = make_float4(0.f, 0.f, 0.f, 0.f);
        if (bBase) bv = *(const float4*)(bBase + k);
        __syncthreads();   // previous iteration's compute done
        As[lc + 0][lr] = av.x; As[lc + 1][lr] = av.y;
        As[lc + 2][lr] = av.z; As[lc + 3][lr] = av.w;
        Bs[lc + 0][lr] = bv.x; Bs[lc + 1][lr] = bv.y;
        Bs[lc + 2][lr] = bv.z; Bs[lc + 3][lr] = bv.w;
        __syncthreads();
#pragma unroll
        for (int kk = 0; kk < 16; ++kk) {
            const float4 a4 = *(const float4*)&As[kk][ty * 4];
            const float4 b4 = *(const float4*)&Bs[kk][tx * 4];
            acc[0][0] += a4.x * b4.x; acc[0][1] += a4.x * b4.y;
            acc[0][2] += a4.x * b4.z; acc[0][3] += a4.x * b4.w;
            acc[1][0] += a4.y * b4.x; acc[1][1] += a4.y * b4.y;
            acc[1][2] += a4.y * b4.z; acc[1][3] += a4.y * b4.w;
            acc[2][0] += a4.z * b4.x; acc[2][1] += a4.z * b4.y;
            acc[2][2] += a4.z * b4.z; acc[2][3] += a4.z * b4.w;
            acc[3][0] += a4.w * b4.x; acc[3][1] += a4.w * b4.y;
            acc[3][2] += a4.w * b4.z; acc[3][3] += a4.w * b4.w;
        }
    }
    __syncthreads();

    float* Cp = C + (size_t)blockIdx.z * gridDim.x * 64 * ldc;
#pragma unroll
    for (int i = 0; i < 4; ++i) {
        const int r = row0 + ty * 4 + i;
#pragma unroll
        for (int j = 0; j < 4; ++j) {
            const int cc = col0 + tx * 4 + j;
            if (cc < Ncols) {
                float v = acc[i][j];
                if (bias) v += bias[cc];
                Cp[(size_t)r * ldc + cc] = v;
            }
        }
    }
}

// x = [w_emb | h | z] with w_emb = sum of 8 partials + E_b
__global__ __launch_bounds__(256) void build_x(
    const float* __restrict__ embp, const float* __restrict__ E_b,
    const float* __restrict__ h, const float* __restrict__ z,
    float* __restrict__ x)
{
    const int idx = blockIdx.x * 256 + threadIdx.x;   // < B*2048
    const int b = idx >> 11, j = idx & 2047;
    float v;
    if (j < 512) {
        v = E_b[j];
#pragma unroll
        for (int s = 0; s < 8; ++s) v += embp[(size_t)s * BB * 512 + (size_t)b * 512 + j];
    } else if (j < 1536) {
        v = h[(size_t)b * NN + (j - 512)];
    } else {
        v = z[(size_t)b * DD + (j - 1536)];
    }
    x[idx] = v;
}

__global__ __launch_bounds__(256) void lstm_cell(
    const float* __restrict__ ihp, const float* __restrict__ hhp,
    const float* __restrict__ b_ih, const float* __restrict__ b_hh,
    const float* __restrict__ c_prev, float* __restrict__ hn, float* __restrict__ cn)
{
    const int idx = blockIdx.x * 256 + threadIdx.x;   // < B*1024
    const int b = idx >> 10, n = idx & 1023;
    float g[4];
#pragma unroll
    for (int gi = 0; gi < 4; ++gi) {
        const int col = gi * 1024 + n;
        const size_t o = (size_t)b * 4096 + col;
        g[gi] = ihp[o] + ihp[(size_t)BB * 4096 + o] + hhp[o] + b_ih[col] + b_hh[col];
    }
    const float si = 1.f / (1.f + expf(-g[0]));
    const float sf = 1.f / (1.f + expf(-g[1]));
    const float so = 1.f / (1.f + expf(-g[3]));
    const float tg = tanhf(g[2]);
    const float c = c_prev[idx];
    const float cnv = sf * c + si * tg;
    const float hnv = so * tanhf(cnv);
    cn[idx] = cnv;
    hn[idx] = hnv;
}

// deep = w_emb + sum(lh partials) + sum(lz partials) + Lh_b + Lz_b
__global__ __launch_bounds__(256) void build_deep(
    const float* __restrict__ x, const float* __restrict__ lhp,
    const float* __restrict__ lzp, const float* __restrict__ Lh_b,
    const float* __restrict__ Lz_b, float* __restrict__ deep)
{
    const int idx = blockIdx.x * 256 + threadIdx.x;   // < B*512
    const int b = idx >> 9, j = idx & 511;
    float v = x[(size_t)b * 2048 + j] + Lh_b[j] + Lz_b[j];
#pragma unroll
    for (int s = 0; s < 4; ++s) v += lhp[(size_t)s * BB * 512 + idx];
#pragma unroll
    for (int s = 0; s < 2; ++s) v += lzp[(size_t)s * BB * 512 + idx];
    deep[idx] = v;
}

extern "C" void kernel_launch(void* const* d_in, const int* in_sizes, int n_in,
                              void* d_out, int out_size, void* d_ws, size_t ws_size,
                              hipStream_t stream)
{
    const float* a_i     = (const float*)d_in[0];
    const float* inp     = (const float*)d_in[1];
    const float* hn_prev = (const float*)d_in[2];
    const float* cn_prev = (const float*)d_in[3];
    const float* f_att_w = (const float*)d_in[4];
    const float* f_att_b = (const float*)d_in[5];
    const float* gate_w  = (const float*)d_in[6];
    const float* gate_b  = (const float*)d_in[7];
    const float* E_w     = (const float*)d_in[8];
    const float* E_b     = (const float*)d_in[9];
    const float* W_ih    = (const float*)d_in[10];
    const float* W_hh    = (const float*)d_in[11];
    const float* b_ih    = (const float*)d_in[12];
    const float* b_hh    = (const float*)d_in[13];
    const float* Lh_w    = (const float*)d_in[14];
    const float* Lh_b    = (const float*)d_in[15];
    const float* Lz_w    = (const float*)d_in[16];
    const float* Lz_b    = (const float*)d_in[17];
    const float* Lo_w    = (const float*)d_in[18];
    const float* Lo_b    = (const float*)d_in[19];

    float* out = (float*)d_out;
    float* ws  = (float*)d_ws;

    // attention
    att_e_partial<<<dim3(BB, 4), 256, 0, stream>>>(a_i, f_att_w, ws + OFF_PE);
    att_softmax<<<BB, 256, 0, stream>>>(ws + OFF_PE, hn_prev, f_att_w, f_att_b,
                                        gate_w, gate_b, out + OUT_AL, ws + OFF_BETA);
    att_z<<<dim3(BB, DD / 4), 256, 0, stream>>>(a_i, out + OUT_AL, ws + OFF_BETA, ws + OFF_Z);

    // w_emb = inp @ E_w.T : K=10000 (625 k-tiles), split-K 8
    gemm_tn<<<dim3(4, 8, 8), 256, 0, stream>>>(inp, KK, E_w, KK,
                                               ws + OFF_EMBP, MM, MM, KK, 79, nullptr);
    build_x<<<BB * 2048 / 256, 256, 0, stream>>>(ws + OFF_EMBP, E_b, hn_prev,
                                                 ws + OFF_Z, ws + OFF_X);

    // gates = x @ W_ih.T (split-K 2) + h @ W_hh.T
    gemm_tn<<<dim3(4, 64, 2), 256, 0, stream>>>(ws + OFF_X, 2048, W_ih, 2048,
                                                ws + OFF_IHP, 4096, 4096, 2048, 64, nullptr);
    gemm_tn<<<dim3(4, 64, 1), 256, 0, stream>>>(hn_prev, NN, W_hh, NN,
                                                ws + OFF_HHP, 4096, 4096, NN, 64, nullptr);
    lstm_cell<<<BB * NN / 256, 256, 0, stream>>>(ws + OFF_IHP, ws + OFF_HHP, b_ih, b_hh,
                                                 cn_prev, out + OUT_HN, out + OUT_CN);

    // deep_out = w_emb + hn @ Lh_w.T + Lh_b + z @ Lz_w.T + Lz_b
    gemm_tn<<<dim3(4, 8, 4), 256, 0, stream>>>(out + OUT_HN, NN, Lh_w, NN,
                                               ws + OFF_LHP, MM, MM, NN, 16, nullptr);
    gemm_tn<<<dim3(4, 8, 2), 256, 0, stream>>>(ws + OFF_Z, DD, Lz_w, DD,
                                               ws + OFF_LZP, MM, MM, DD, 16, nullptr);
    build_deep<<<BB * MM / 256, 256, 0, stream>>>(ws + OFF_X, ws + OFF_LHP, ws + OFF_LZP,
                                                  Lh_b, Lz_b, ws + OFF_DEEP);

    // p_yt = deep @ Lo_w.T + Lo_b  (N=10000, guarded)
    gemm_tn<<<dim3(4, 157, 1), 256, 0, stream>>>(ws + OFF_DEEP, MM, Lo_w, MM,
                                                 out + OUT_PY, KK, KK, MM, 32, Lo_b);
}

// Round 2
// 228.554 us; speedup vs baseline: 1.6607x; 1.6607x over previous
//
#include <hip/hip_runtime.h>
#include <hip/hip_bf16.h>
#include <math.h>

// Problem constants
#define BB 256
#define DD 512
#define LL 196
#define NN 1024
#define MM 512
#define KK 10000

// ---- workspace layout (float offsets) ----
#define OFF_PE    ((size_t)0)               // B*4*L       = 200704
#define OFF_BETA  ((size_t)200704)          // B           = 256
#define OFF_Z     ((size_t)200960)          // B*D         = 131072
#define OFF_EMBP  ((size_t)332032)          // 8*B*M       = 1048576
#define OFF_X     ((size_t)1380608)         // B*2048      = 524288
#define OFF_IHP   ((size_t)1904896)         // 2*B*4096    = 2097152
#define OFF_HHP   ((size_t)4002048)         // 2*B*4096    = 2097152
#define OFF_LHP   ((size_t)6099200)         // 4*B*M       = 524288
#define OFF_LZP   ((size_t)6623488)         // 2*B*M       = 262144
#define OFF_DEEP  ((size_t)6885632)         // B*M         = 131072
// total = 7016704 floats = 28.1 MB

// ---- output layout (float offsets) ----
#define OUT_PY 0
#define OUT_HN ((size_t)2560000)
#define OUT_CN ((size_t)2822144)
#define OUT_AL ((size_t)3084288)

typedef __attribute__((ext_vector_type(8))) short short8v;
typedef __attribute__((ext_vector_type(4))) float f32x4;

__device__ __forceinline__ unsigned short f2bf(float f) {
    unsigned int u = __builtin_bit_cast(unsigned int, f);
    u += 0x7fffu + ((u >> 16) & 1u);            // round-to-nearest-even
    return (unsigned short)(u >> 16);
}

// load 8 k-contiguous floats (guarded) -> bf16x8
__device__ __forceinline__ short8v stage8(const float* __restrict__ p, bool ok,
                                          int kbase, int Ktot) {
    short8v v;
    if (ok && (kbase + 7 < Ktot)) {
        const float4 x = *(const float4*)(p + kbase);
        const float4 y = *(const float4*)(p + kbase + 4);
        v[0] = (short)f2bf(x.x); v[1] = (short)f2bf(x.y);
        v[2] = (short)f2bf(x.z); v[3] = (short)f2bf(x.w);
        v[4] = (short)f2bf(y.x); v[5] = (short)f2bf(y.y);
        v[6] = (short)f2bf(y.z); v[7] = (short)f2bf(y.w);
    } else {
#pragma unroll
        for (int i = 0; i < 8; ++i) {
            const int k = kbase + i;
            const float f = (ok && k < Ktot) ? p[k] : 0.f;
            v[i] = (short)f2bf(f);
        }
    }
    return v;
}

// e_partial: pe[b][ch][l] = sum_{d in chunk ch} a_i[b,d,l] * w_a[d]
__global__ __launch_bounds__(256) void att_e_partial(
    const float* __restrict__ a_i, const float* __restrict__ f_att_w,
    float* __restrict__ pe)
{
    const int b = blockIdx.x, ch = blockIdx.y;
    const int l = threadIdx.x;
    if (l >= LL) return;
    const float* ap = a_i + ((size_t)b * DD + ch * 128) * LL + l;
    const float* wp = f_att_w + ch * 128;
    float s = 0.f;
#pragma unroll 8
    for (int d = 0; d < 128; ++d) s += ap[(size_t)d * LL] * wp[d];
    pe[((size_t)b * 4 + ch) * LL + l] = s;
}

// per-b: hdot = h.w_h, gdot = h.gate_w, e = sum(pe)+hdot+bias, softmax -> alpha; beta = sigmoid(gdot+gb)
__global__ __launch_bounds__(256) void att_softmax(
    const float* __restrict__ pe, const float* __restrict__ h,
    const float* __restrict__ f_att_w, const float* __restrict__ f_att_b,
    const float* __restrict__ gate_w, const float* __restrict__ gate_b,
    float* __restrict__ alpha_out, float* __restrict__ beta)
{
    const int b = blockIdx.x;
    const int t = threadIdx.x;
    __shared__ float red[256];
    __shared__ float red2[256];

    const float4 h4 = *(const float4*)(h + (size_t)b * NN + t * 4);
    const float4 w4 = *(const float4*)(f_att_w + DD + t * 4);
    const float4 g4 = *(const float4*)(gate_w + t * 4);
    float hd = h4.x * w4.x + h4.y * w4.y + h4.z * w4.z + h4.w * w4.w;
    float gd = h4.x * g4.x + h4.y * g4.y + h4.z * g4.z + h4.w * g4.w;
    red[t] = hd; red2[t] = gd;
    __syncthreads();
    for (int s = 128; s > 0; s >>= 1) {
        if (t < s) { red[t] += red[t + s]; red2[t] += red2[t + s]; }
        __syncthreads();
    }
    const float hdot = red[0];
    const float gdot = red2[0];
    __syncthreads();

    float e = -1e30f;
    if (t < LL) {
        const float* p = pe + (size_t)b * 4 * LL + t;
        e = p[0] + p[LL] + p[2 * LL] + p[3 * LL] + hdot + f_att_b[0];
    }
    red[t] = e;
    __syncthreads();
    for (int s = 128; s > 0; s >>= 1) {
        if (t < s) red[t] = fmaxf(red[t], red[t + s]);
        __syncthreads();
    }
    const float mx = red[0];
    __syncthreads();
    const float ex = (t < LL) ? expf(e - mx) : 0.f;
    red[t] = ex;
    __syncthreads();
    for (int s = 128; s > 0; s >>= 1) {
        if (t < s) red[t] += red[t + s];
        __syncthreads();
    }
    const float inv = 1.f / red[0];
    if (t < LL) alpha_out[(size_t)b * LL + t] = ex * inv;
    if (t == 0) beta[b] = 1.f / (1.f + expf(-(gdot + gate_b[0])));
}

// z[b,d] = beta[b] * sum_l alpha[b,l] * a_i[b,d,l] ; one wave per d
__global__ __launch_bounds__(256) void att_z(
    const float* __restrict__ a_i, const float* __restrict__ alpha,
    const float* __restrict__ beta, float* __restrict__ z)
{
    const int b = blockIdx.x;
    const int wave = threadIdx.x >> 6, lane = threadIdx.x & 63;
    const int d = blockIdx.y * 4 + wave;
    const float* ap = a_i + ((size_t)b * DD + d) * LL;
    const float* alp = alpha + (size_t)b * LL;
    float s = 0.f;
    for (int l = lane; l < LL; l += 64) s += ap[l] * alp[l];
#pragma unroll
    for (int off = 32; off > 0; off >>= 1) s += __shfl_down(s, off, 64);
    if (lane == 0) z[(size_t)b * DD + d] = beta[b] * s;
}

// TN GEMM via bf16 MFMA: C[r,c] = sum_k A[r,k] * Bw[c,k], fp32 in/out.
// 64x64 tile, BK=32, 256 threads (4 waves as 2x2 of 32x32), split-K via
// blockIdx.z writing partials at C + z*(gridDim.x*64)*ldc.
// LDS tiles [64][56] bf16: 112B row stride (16B-aligned, 2-way bank alias only).
__global__ __launch_bounds__(256) void gemm_tn_mfma(
    const float* __restrict__ A, int lda,
    const float* __restrict__ Bw, int ldb,
    float* __restrict__ C, int ldc,
    int Ncols, int Ktot, int ktPerSplit,
    const float* __restrict__ bias)
{
    __shared__ __align__(16) short As[2][64][56];
    __shared__ __align__(16) short Bs[2][64][56];
    const int t = threadIdx.x;
    const int row0 = blockIdx.x * 64;
    const int col0 = blockIdx.y * 64;
    const int ktTot = (Ktot + 31) >> 5;
    const int kt0 = blockIdx.z * ktPerSplit;
    const int nk = min(ktTot, kt0 + ktPerSplit) - kt0;

    // staging coords: thread t loads 8 k-contiguous elems of row sr
    const int sr = t >> 2;
    const int sk = (t & 3) << 3;
    const float* aP = A + (size_t)(row0 + sr) * lda;
    const int bc = col0 + sr;
    const bool bok = (bc < Ncols);
    const float* bP = Bw + (size_t)(bok ? bc : 0) * ldb;

    // fragment coords
    const int l = t & 63, w = t >> 6;
    const int wrow = (w >> 1) * 32, wcol = (w & 1) * 32;
    const int lr = l & 15, g = l >> 4, g8 = g * 8;

    f32x4 acc[2][2] = {};

    int k0 = kt0 << 5;
    short8v sa = stage8(aP, true, k0 + sk, Ktot);
    short8v sb = stage8(bP, bok, k0 + sk, Ktot);
    *(short8v*)&As[0][sr][sk] = sa;
    *(short8v*)&Bs[0][sr][sk] = sb;
    __syncthreads();

    int cur = 0;
    for (int kt = 0; kt < nk; ++kt) {
        const bool more = (kt + 1 < nk);
        if (more) {
            k0 = (kt0 + kt + 1) << 5;
            sa = stage8(aP, true, k0 + sk, Ktot);
            sb = stage8(bP, bok, k0 + sk, Ktot);
        }
        short8v a0 = *(const short8v*)&As[cur][wrow + lr][g8];
        short8v a1 = *(const short8v*)&As[cur][wrow + 16 + lr][g8];
        short8v b0 = *(const short8v*)&Bs[cur][wcol + lr][g8];
        short8v b1 = *(const short8v*)&Bs[cur][wcol + 16 + lr][g8];
        acc[0][0] = __builtin_amdgcn_mfma_f32_16x16x32_bf16(a0, b0, acc[0][0], 0, 0, 0);
        acc[0][1] = __builtin_amdgcn_mfma_f32_16x16x32_bf16(a0, b1, acc[0][1], 0, 0, 0);
        acc[1][0] = __builtin_amdgcn_mfma_f32_16x16x32_bf16(a1, b0, acc[1][0], 0, 0, 0);
        acc[1][1] = __builtin_amdgcn_mfma_f32_16x16x32_bf16(a1, b1, acc[1][1], 0, 0, 0);
        if (more) {
            *(short8v*)&As[cur ^ 1][sr][sk] = sa;
            *(short8v*)&Bs[cur ^ 1][sr][sk] = sb;
        }
        __syncthreads();
        cur ^= 1;
    }

    float* Cp = C + (size_t)blockIdx.z * ((size_t)gridDim.x * 64) * ldc;
#pragma unroll
    for (int m = 0; m < 2; ++m)
#pragma unroll
        for (int n = 0; n < 2; ++n)
#pragma unroll
            for (int j = 0; j < 4; ++j) {
                const int r = row0 + wrow + m * 16 + g * 4 + j;
                const int c = col0 + wcol + n * 16 + lr;
                if (c < Ncols) {
                    float v = acc[m][n][j];
                    if (bias) v += bias[c];
                    Cp[(size_t)r * ldc + c] = v;
                }
            }
}

// x = [w_emb | h | z] with w_emb = sum of 8 partials + E_b
__global__ __launch_bounds__(256) void build_x(
    const float* __restrict__ embp, const float* __restrict__ E_b,
    const float* __restrict__ h, const float* __restrict__ z,
    float* __restrict__ x)
{
    const int idx = blockIdx.x * 256 + threadIdx.x;   // < B*2048
    const int b = idx >> 11, j = idx & 2047;
    float v;
    if (j < 512) {
        v = E_b[j];
#pragma unroll
        for (int s = 0; s < 8; ++s) v += embp[(size_t)s * BB * 512 + (size_t)b * 512 + j];
    } else if (j < 1536) {
        v = h[(size_t)b * NN + (j - 512)];
    } else {
        v = z[(size_t)b * DD + (j - 1536)];
    }
    x[idx] = v;
}

__global__ __launch_bounds__(256) void lstm_cell(
    const float* __restrict__ ihp, const float* __restrict__ hhp,
    const float* __restrict__ b_ih, const float* __restrict__ b_hh,
    const float* __restrict__ c_prev, float* __restrict__ hn, float* __restrict__ cn)
{
    const int idx = blockIdx.x * 256 + threadIdx.x;   // < B*1024
    const int b = idx >> 10, n = idx & 1023;
    float g[4];
#pragma unroll
    for (int gi = 0; gi < 4; ++gi) {
        const int col = gi * 1024 + n;
        const size_t o = (size_t)b * 4096 + col;
        g[gi] = ihp[o] + ihp[(size_t)BB * 4096 + o]
              + hhp[o] + hhp[(size_t)BB * 4096 + o]
              + b_ih[col] + b_hh[col];
    }
    const float si = 1.f / (1.f + expf(-g[0]));
    const float sf = 1.f / (1.f + expf(-g[1]));
    const float so = 1.f / (1.f + expf(-g[3]));
    const float tg = tanhf(g[2]);
    const float c = c_prev[idx];
    const float cnv = sf * c + si * tg;
    const float hnv = so * tanhf(cnv);
    cn[idx] = cnv;
    hn[idx] = hnv;
}

// deep = w_emb + sum(lh partials, 4) + sum(lz partials, 2) + Lh_b + Lz_b
__global__ __launch_bounds__(256) void build_deep(
    const float* __restrict__ x, const float* __restrict__ lhp,
    const float* __restrict__ lzp, const float* __restrict__ Lh_b,
    const float* __restrict__ Lz_b, float* __restrict__ deep)
{
    const int idx = blockIdx.x * 256 + threadIdx.x;   // < B*512
    const int b = idx >> 9, j = idx & 511;
    float v = x[(size_t)b * 2048 + j] + Lh_b[j] + Lz_b[j];
#pragma unroll
    for (int s = 0; s < 4; ++s) v += lhp[(size_t)s * BB * 512 + idx];
#pragma unroll
    for (int s = 0; s < 2; ++s) v += lzp[(size_t)s * BB * 512 + idx];
    deep[idx] = v;
}

extern "C" void kernel_launch(void* const* d_in, const int* in_sizes, int n_in,
                              void* d_out, int out_size, void* d_ws, size_t ws_size,
                              hipStream_t stream)
{
    const float* a_i     = (const float*)d_in[0];
    const float* inp     = (const float*)d_in[1];
    const float* hn_prev = (const float*)d_in[2];
    const float* cn_prev = (const float*)d_in[3];
    const float* f_att_w = (const float*)d_in[4];
    const float* f_att_b = (const float*)d_in[5];
    const float* gate_w  = (const float*)d_in[6];
    const float* gate_b  = (const float*)d_in[7];
    const float* E_w     = (const float*)d_in[8];
    const float* E_b     = (const float*)d_in[9];
    const float* W_ih    = (const float*)d_in[10];
    const float* W_hh    = (const float*)d_in[11];
    const float* b_ih    = (const float*)d_in[12];
    const float* b_hh    = (const float*)d_in[13];
    const float* Lh_w    = (const float*)d_in[14];
    const float* Lh_b    = (const float*)d_in[15];
    const float* Lz_w    = (const float*)d_in[16];
    const float* Lz_b    = (const float*)d_in[17];
    const float* Lo_w    = (const float*)d_in[18];
    const float* Lo_b    = (const float*)d_in[19];

    float* out = (float*)d_out;
    float* ws  = (float*)d_ws;

    // attention
    att_e_partial<<<dim3(BB, 4), 256, 0, stream>>>(a_i, f_att_w, ws + OFF_PE);
    att_softmax<<<BB, 256, 0, stream>>>(ws + OFF_PE, hn_prev, f_att_w, f_att_b,
                                        gate_w, gate_b, out + OUT_AL, ws + OFF_BETA);
    att_z<<<dim3(BB, DD / 4), 256, 0, stream>>>(a_i, out + OUT_AL, ws + OFF_BETA, ws + OFF_Z);

    // w_emb = inp @ E_w.T : K=10000 (313 k-tiles of 32), split-K 8
    gemm_tn_mfma<<<dim3(4, 8, 8), 256, 0, stream>>>(inp, KK, E_w, KK,
                                                    ws + OFF_EMBP, MM, MM, KK, 40, nullptr);
    build_x<<<BB * 2048 / 256, 256, 0, stream>>>(ws + OFF_EMBP, E_b, hn_prev,
                                                 ws + OFF_Z, ws + OFF_X);

    // gates = x @ W_ih.T (split-K 2) + h @ W_hh.T (split-K 2)
    gemm_tn_mfma<<<dim3(4, 64, 2), 256, 0, stream>>>(ws + OFF_X, 2048, W_ih, 2048,
                                                     ws + OFF_IHP, 4096, 4096, 2048, 32, nullptr);
    gemm_tn_mfma<<<dim3(4, 64, 2), 256, 0, stream>>>(hn_prev, NN, W_hh, NN,
                                                     ws + OFF_HHP, 4096, 4096, NN, 16, nullptr);
    lstm_cell<<<BB * NN / 256, 256, 0, stream>>>(ws + OFF_IHP, ws + OFF_HHP, b_ih, b_hh,
                                                 cn_prev, out + OUT_HN, out + OUT_CN);

    // deep_out = w_emb + hn @ Lh_w.T + Lh_b + z @ Lz_w.T + Lz_b
    gemm_tn_mfma<<<dim3(4, 8, 4), 256, 0, stream>>>(out + OUT_HN, NN, Lh_w, NN,
                                                    ws + OFF_LHP, MM, MM, NN, 8, nullptr);
    gemm_tn_mfma<<<dim3(4, 8, 2), 256, 0, stream>>>(ws + OFF_Z, DD, Lz_w, DD,
                                                    ws + OFF_LZP, MM, MM, DD, 8, nullptr);
    build_deep<<<BB * MM / 256, 256, 0, stream>>>(ws + OFF_X, ws + OFF_LHP, ws + OFF_LZP,
                                                  Lh_b, Lz_b, ws + OFF_DEEP);

    // p_yt = deep @ Lo_w.T + Lo_b  (Ncols=10000, guarded)
    gemm_tn_mfma<<<dim3(4, 157, 1), 256, 0, stream>>>(ws + OFF_DEEP, MM, Lo_w, MM,
                                                      out + OUT_PY, KK, KK, MM, 16, Lo_b);
}

// Round 3
// 198.269 us; speedup vs baseline: 1.9144x; 1.1527x over previous
//
#include <hip/hip_runtime.h>
#include <hip/hip_bf16.h>
#include <math.h>

// Problem constants
#define BB 256
#define DD 512
#define LL 196
#define NN 1024
#define MM 512
#define KK 10000

// ---- output layout (float offsets) ----
#define OUT_PY 0
#define OUT_HN ((size_t)2560000)
#define OUT_CN ((size_t)2822144)
#define OUT_AL ((size_t)3084288)

typedef __attribute__((ext_vector_type(8))) short short8v;
typedef __attribute__((ext_vector_type(4))) float f32x4;

__device__ __forceinline__ unsigned short f2bf(float f) {
    unsigned int u = __builtin_bit_cast(unsigned int, f);
    u += 0x7fffu + ((u >> 16) & 1u);            // round-to-nearest-even
    return (unsigned short)(u >> 16);
}

// load 8 k-contiguous floats (guarded) -> bf16x8
__device__ __forceinline__ short8v stage8(const float* __restrict__ p, bool ok,
                                          int kbase, int Ktot) {
    short8v v;
    if (ok && (kbase + 7 < Ktot)) {
        const float4 x = *(const float4*)(p + kbase);
        const float4 y = *(const float4*)(p + kbase + 4);
        v[0] = (short)f2bf(x.x); v[1] = (short)f2bf(x.y);
        v[2] = (short)f2bf(x.z); v[3] = (short)f2bf(x.w);
        v[4] = (short)f2bf(y.x); v[5] = (short)f2bf(y.y);
        v[6] = (short)f2bf(y.z); v[7] = (short)f2bf(y.w);
    } else {
#pragma unroll
        for (int i = 0; i < 8; ++i) {
            const int k = kbase + i;
            const float f = (ok && k < Ktot) ? p[k] : 0.f;
            v[i] = (short)f2bf(f);
        }
    }
    return v;
}

// e_partial: pe[b][ch][l] = sum_{d in chunk ch} a_i[b,d,l] * w_a[d]
__global__ __launch_bounds__(256) void att_e_partial(
    const float* __restrict__ a_i, const float* __restrict__ f_att_w,
    float* __restrict__ pe)
{
    const int b = blockIdx.x, ch = blockIdx.y;
    const int l = threadIdx.x;
    if (l >= LL) return;
    const float* ap = a_i + ((size_t)b * DD + ch * 128) * LL + l;
    const float* wp = f_att_w + ch * 128;
    float s = 0.f;
#pragma unroll 8
    for (int d = 0; d < 128; ++d) s += ap[(size_t)d * LL] * wp[d];
    pe[((size_t)b * 4 + ch) * LL + l] = s;
}

// per-b: hdot = h.w_h, gdot = h.gate_w, e = sum(pe)+hdot+bias, softmax -> alpha; beta = sigmoid(gdot+gb)
__global__ __launch_bounds__(256) void att_softmax(
    const float* __restrict__ pe, const float* __restrict__ h,
    const float* __restrict__ f_att_w, const float* __restrict__ f_att_b,
    const float* __restrict__ gate_w, const float* __restrict__ gate_b,
    float* __restrict__ alpha_out, float* __restrict__ beta)
{
    const int b = blockIdx.x;
    const int t = threadIdx.x;
    __shared__ float red[256];
    __shared__ float red2[256];

    const float4 h4 = *(const float4*)(h + (size_t)b * NN + t * 4);
    const float4 w4 = *(const float4*)(f_att_w + DD + t * 4);
    const float4 g4 = *(const float4*)(gate_w + t * 4);
    float hd = h4.x * w4.x + h4.y * w4.y + h4.z * w4.z + h4.w * w4.w;
    float gd = h4.x * g4.x + h4.y * g4.y + h4.z * g4.z + h4.w * g4.w;
    red[t] = hd; red2[t] = gd;
    __syncthreads();
    for (int s = 128; s > 0; s >>= 1) {
        if (t < s) { red[t] += red[t + s]; red2[t] += red2[t + s]; }
        __syncthreads();
    }
    const float hdot = red[0];
    const float gdot = red2[0];
    __syncthreads();

    float e = -1e30f;
    if (t < LL) {
        const float* p = pe + (size_t)b * 4 * LL + t;
        e = p[0] + p[LL] + p[2 * LL] + p[3 * LL] + hdot + f_att_b[0];
    }
    red[t] = e;
    __syncthreads();
    for (int s = 128; s > 0; s >>= 1) {
        if (t < s) red[t] = fmaxf(red[t], red[t + s]);
        __syncthreads();
    }
    const float mx = red[0];
    __syncthreads();
    const float ex = (t < LL) ? expf(e - mx) : 0.f;
    red[t] = ex;
    __syncthreads();
    for (int s = 128; s > 0; s >>= 1) {
        if (t < s) red[t] += red[t + s];
        __syncthreads();
    }
    const float inv = 1.f / red[0];
    if (t < LL) alpha_out[(size_t)b * LL + t] = ex * inv;
    if (t == 0) beta[b] = 1.f / (1.f + expf(-(gdot + gate_b[0])));
}

// z[b,d] = beta[b] * sum_l alpha[b,l] * a_i[b,d,l] ; one wave per d
__global__ __launch_bounds__(256) void att_z(
    const float* __restrict__ a_i, const float* __restrict__ alpha,
    const float* __restrict__ beta, float* __restrict__ z)
{
    const int b = blockIdx.x;
    const int wave = threadIdx.x >> 6, lane = threadIdx.x & 63;
    const int d = blockIdx.y * 4 + wave;
    const float* ap = a_i + ((size_t)b * DD + d) * LL;
    const float* alp = alpha + (size_t)b * LL;
    float s = 0.f;
    for (int l = lane; l < LL; l += 64) s += ap[l] * alp[l];
#pragma unroll
    for (int off = 32; off > 0; off >>= 1) s += __shfl_down(s, off, 64);
    if (lane == 0) z[(size_t)b * DD + d] = beta[b] * s;
}

// TN GEMM via bf16 MFMA: C[r,c] = sum_k A[r,k] * Bw[c,k], fp32 in/out.
// 64x64 tile, BK=32, 256 threads (4 waves as 2x2 of 32x32), split-K via
// blockIdx.z writing partials at C + z*(gridDim.x*64)*ldc.
__global__ __launch_bounds__(256) void gemm_tn_mfma(
    const float* __restrict__ A, int lda,
    const float* __restrict__ Bw, int ldb,
    float* __restrict__ C, int ldc,
    int Ncols, int Ktot, int ktPerSplit,
    const float* __restrict__ bias)
{
    __shared__ __align__(16) short As[2][64][56];
    __shared__ __align__(16) short Bs[2][64][56];
    const int t = threadIdx.x;
    const int row0 = blockIdx.x * 64;
    const int col0 = blockIdx.y * 64;
    const int ktTot = (Ktot + 31) >> 5;
    const int kt0 = blockIdx.z * ktPerSplit;
    const int nk = min(ktTot, kt0 + ktPerSplit) - kt0;

    // staging coords: thread t loads 8 k-contiguous elems of row sr
    const int sr = t >> 2;
    const int sk = (t & 3) << 3;
    const float* aP = A + (size_t)(row0 + sr) * lda;
    const int bc = col0 + sr;
    const bool bok = (bc < Ncols);
    const float* bP = Bw + (size_t)(bok ? bc : 0) * ldb;

    // fragment coords
    const int l = t & 63, w = t >> 6;
    const int wrow = (w >> 1) * 32, wcol = (w & 1) * 32;
    const int lr = l & 15, g = l >> 4, g8 = g * 8;

    f32x4 acc[2][2] = {};

    int k0 = kt0 << 5;
    short8v sa = stage8(aP, true, k0 + sk, Ktot);
    short8v sb = stage8(bP, bok, k0 + sk, Ktot);
    *(short8v*)&As[0][sr][sk] = sa;
    *(short8v*)&Bs[0][sr][sk] = sb;
    __syncthreads();

    int cur = 0;
    for (int kt = 0; kt < nk; ++kt) {
        const bool more = (kt + 1 < nk);
        if (more) {
            k0 = (kt0 + kt + 1) << 5;
            sa = stage8(aP, true, k0 + sk, Ktot);
            sb = stage8(bP, bok, k0 + sk, Ktot);
        }
        short8v a0 = *(const short8v*)&As[cur][wrow + lr][g8];
        short8v a1 = *(const short8v*)&As[cur][wrow + 16 + lr][g8];
        short8v b0 = *(const short8v*)&Bs[cur][wcol + lr][g8];
        short8v b1 = *(const short8v*)&Bs[cur][wcol + 16 + lr][g8];
        acc[0][0] = __builtin_amdgcn_mfma_f32_16x16x32_bf16(a0, b0, acc[0][0], 0, 0, 0);
        acc[0][1] = __builtin_amdgcn_mfma_f32_16x16x32_bf16(a0, b1, acc[0][1], 0, 0, 0);
        acc[1][0] = __builtin_amdgcn_mfma_f32_16x16x32_bf16(a1, b0, acc[1][0], 0, 0, 0);
        acc[1][1] = __builtin_amdgcn_mfma_f32_16x16x32_bf16(a1, b1, acc[1][1], 0, 0, 0);
        if (more) {
            *(short8v*)&As[cur ^ 1][sr][sk] = sa;
            *(short8v*)&Bs[cur ^ 1][sr][sk] = sb;
        }
        __syncthreads();
        cur ^= 1;
    }

    float* Cp = C + (size_t)blockIdx.z * ((size_t)gridDim.x * 64) * ldc;
#pragma unroll
    for (int m = 0; m < 2; ++m)
#pragma unroll
        for (int n = 0; n < 2; ++n)
#pragma unroll
            for (int j = 0; j < 4; ++j) {
                const int r = row0 + wrow + m * 16 + g * 4 + j;
                const int c = col0 + wcol + n * 16 + lr;
                if (c < Ncols) {
                    float v = acc[m][n][j];
                    if (bias) v += bias[c];
                    Cp[(size_t)r * ldc + c] = v;
                }
            }
}

// x = [w_emb | h | z] with w_emb = sum of nEmb partials + E_b
__global__ __launch_bounds__(256) void build_x(
    const float* __restrict__ embp, int nEmb, const float* __restrict__ E_b,
    const float* __restrict__ h, const float* __restrict__ z,
    float* __restrict__ x)
{
    const int idx = blockIdx.x * 256 + threadIdx.x;   // < B*2048
    const int b = idx >> 11, j = idx & 2047;
    float v;
    if (j < 512) {
        v = E_b[j];
        for (int s = 0; s < nEmb; ++s) v += embp[(size_t)s * BB * 512 + (size_t)b * 512 + j];
    } else if (j < 1536) {
        v = h[(size_t)b * NN + (j - 512)];
    } else {
        v = z[(size_t)b * DD + (j - 1536)];
    }
    x[idx] = v;
}

__global__ __launch_bounds__(256) void lstm_cell(
    const float* __restrict__ ihp, int nIh,
    const float* __restrict__ hhp, int nHh,
    const float* __restrict__ b_ih, const float* __restrict__ b_hh,
    const float* __restrict__ c_prev, float* __restrict__ hn, float* __restrict__ cn)
{
    const int idx = blockIdx.x * 256 + threadIdx.x;   // < B*1024
    const int b = idx >> 10, n = idx & 1023;
    float g[4];
#pragma unroll
    for (int gi = 0; gi < 4; ++gi) {
        const int col = gi * 1024 + n;
        const size_t o = (size_t)b * 4096 + col;
        float v = b_ih[col] + b_hh[col];
        for (int s = 0; s < nIh; ++s) v += ihp[(size_t)s * BB * 4096 + o];
        for (int s = 0; s < nHh; ++s) v += hhp[(size_t)s * BB * 4096 + o];
        g[gi] = v;
    }
    const float si = 1.f / (1.f + expf(-g[0]));
    const float sf = 1.f / (1.f + expf(-g[1]));
    const float so = 1.f / (1.f + expf(-g[3]));
    const float tg = tanhf(g[2]);
    const float c = c_prev[idx];
    const float cnv = sf * c + si * tg;
    const float hnv = so * tanhf(cnv);
    cn[idx] = cnv;
    hn[idx] = hnv;
}

// deep = w_emb + sum(lh partials) + sum(lz partials) + Lh_b + Lz_b
__global__ __launch_bounds__(256) void build_deep(
    const float* __restrict__ x, const float* __restrict__ lhp, int nLh,
    const float* __restrict__ lzp, int nLz, const float* __restrict__ Lh_b,
    const float* __restrict__ Lz_b, float* __restrict__ deep)
{
    const int idx = blockIdx.x * 256 + threadIdx.x;   // < B*512
    const int b = idx >> 9, j = idx & 511;
    float v = x[(size_t)b * 2048 + j] + Lh_b[j] + Lz_b[j];
    for (int s = 0; s < nLh; ++s) v += lhp[(size_t)s * BB * 512 + idx];
    for (int s = 0; s < nLz; ++s) v += lzp[(size_t)s * BB * 512 + idx];
    deep[idx] = v;
}

extern "C" void kernel_launch(void* const* d_in, const int* in_sizes, int n_in,
                              void* d_out, int out_size, void* d_ws, size_t ws_size,
                              hipStream_t stream)
{
    const float* a_i     = (const float*)d_in[0];
    const float* inp     = (const float*)d_in[1];
    const float* hn_prev = (const float*)d_in[2];
    const float* cn_prev = (const float*)d_in[3];
    const float* f_att_w = (const float*)d_in[4];
    const float* f_att_b = (const float*)d_in[5];
    const float* gate_w  = (const float*)d_in[6];
    const float* gate_b  = (const float*)d_in[7];
    const float* E_w     = (const float*)d_in[8];
    const float* E_b     = (const float*)d_in[9];
    const float* W_ih    = (const float*)d_in[10];
    const float* W_hh    = (const float*)d_in[11];
    const float* b_ih    = (const float*)d_in[12];
    const float* b_hh    = (const float*)d_in[13];
    const float* Lh_w    = (const float*)d_in[14];
    const float* Lh_b    = (const float*)d_in[15];
    const float* Lz_w    = (const float*)d_in[16];
    const float* Lz_b    = (const float*)d_in[17];
    const float* Lo_w    = (const float*)d_in[18];
    const float* Lo_b    = (const float*)d_in[19];

    float* out = (float*)d_out;
    float* ws  = (float*)d_ws;

    // ---- workspace layout (dynamic, based on ws_size) ----
    // small region: PE | BETA | Z | X | DEEP
    const size_t off_pe   = 0;
    const size_t off_beta = 200704;
    const size_t off_z    = 200960;
    const size_t off_x    = 332032;
    const size_t off_deep = 856320;
    const size_t small_end = 987392;

    const size_t avail = ws_size / sizeof(float);
    // big layout: R1 = max(32 emb slices, 4 ih slices, 8 lh slices) = 4194304
    //             R2 = max(4 hh slices, 4 lz slices)               = 4194304
    const bool big = (avail >= (size_t)9376000);
    const int embS = big ? 32 : 8;
    const int ihS  = big ? 4 : 2;
    const int hhS  = big ? 4 : 2;
    const int lhS  = big ? 8 : 4;
    const int lzS  = big ? 4 : 2;
    const size_t r1sz = big ? (size_t)4194304 : (size_t)2097152;
    const size_t off_r1 = small_end;
    const size_t off_r2 = small_end + r1sz;

    float* EMBP = ws + off_r1;   // embS * B*512
    float* IHP  = ws + off_r1;   // ihS  * B*4096  (after build_x)
    float* LHP  = ws + off_r1;   // lhS  * B*512   (after lstm_cell)
    float* HHP  = ws + off_r2;   // hhS  * B*4096
    float* LZP  = ws + off_r2;   // lzS  * B*512   (after lstm_cell)

    // attention
    att_e_partial<<<dim3(BB, 4), 256, 0, stream>>>(a_i, f_att_w, ws + off_pe);
    att_softmax<<<BB, 256, 0, stream>>>(ws + off_pe, hn_prev, f_att_w, f_att_b,
                                        gate_w, gate_b, out + OUT_AL, ws + off_beta);
    att_z<<<dim3(BB, DD / 4), 256, 0, stream>>>(a_i, out + OUT_AL, ws + off_beta, ws + off_z);

    // w_emb = inp @ E_w.T : K=10000, ktTot=313
    gemm_tn_mfma<<<dim3(4, 8, embS), 256, 0, stream>>>(inp, KK, E_w, KK,
                                                       EMBP, MM, MM, KK,
                                                       (313 + embS - 1) / embS, nullptr);
    build_x<<<BB * 2048 / 256, 256, 0, stream>>>(EMBP, embS, E_b, hn_prev,
                                                 ws + off_z, ws + off_x);

    // gates = x @ W_ih.T + h @ W_hh.T
    gemm_tn_mfma<<<dim3(4, 64, ihS), 256, 0, stream>>>(ws + off_x, 2048, W_ih, 2048,
                                                       IHP, 4096, 4096, 2048, 64 / ihS, nullptr);
    gemm_tn_mfma<<<dim3(4, 64, hhS), 256, 0, stream>>>(hn_prev, NN, W_hh, NN,
                                                       HHP, 4096, 4096, NN, 32 / hhS, nullptr);
    lstm_cell<<<BB * NN / 256, 256, 0, stream>>>(IHP, ihS, HHP, hhS, b_ih, b_hh,
                                                 cn_prev, out + OUT_HN, out + OUT_CN);

    // deep_out = w_emb + hn @ Lh_w.T + Lh_b + z @ Lz_w.T + Lz_b
    gemm_tn_mfma<<<dim3(4, 8, lhS), 256, 0, stream>>>(out + OUT_HN, NN, Lh_w, NN,
                                                      LHP, MM, MM, NN, 32 / lhS, nullptr);
    gemm_tn_mfma<<<dim3(4, 8, lzS), 256, 0, stream>>>(ws + off_z, DD, Lz_w, DD,
                                                      LZP, MM, MM, DD, 16 / lzS, nullptr);
    build_deep<<<BB * MM / 256, 256, 0, stream>>>(ws + off_x, LHP, lhS, LZP, lzS,
                                                  Lh_b, Lz_b, ws + off_deep);

    // p_yt = deep @ Lo_w.T + Lo_b  (Ncols=10000, guarded)
    gemm_tn_mfma<<<dim3(4, 157, 1), 256, 0, stream>>>(ws + off_deep, MM, Lo_w, MM,
                                                      out + OUT_PY, KK, KK, MM, 16, Lo_b);
}

// Round 4
// 182.594 us; speedup vs baseline: 2.0787x; 1.0858x over previous
//
#include <hip/hip_runtime.h>
#include <hip/hip_bf16.h>
#include <math.h>

// Problem constants
#define BB 256
#define DD 512
#define LL 196
#define NN 1024
#define MM 512
#define KK 10000

// ---- output layout (float offsets) ----
#define OUT_PY 0
#define OUT_HN ((size_t)2560000)
#define OUT_CN ((size_t)2822144)
#define OUT_AL ((size_t)3084288)

typedef __attribute__((ext_vector_type(8))) short short8v;
typedef __attribute__((ext_vector_type(4))) float f32x4;

__device__ __forceinline__ unsigned short f2bf(float f) {
    unsigned int u = __builtin_bit_cast(unsigned int, f);
    u += 0x7fffu + ((u >> 16) & 1u);            // round-to-nearest-even
    return (unsigned short)(u >> 16);
}

// load 8 k-contiguous floats (guarded) -> bf16x8
__device__ __forceinline__ short8v stage8(const float* __restrict__ p, bool ok,
                                          int kbase, int Ktot) {
    short8v v;
    if (ok && (kbase + 7 < Ktot)) {
        const float4 x = *(const float4*)(p + kbase);
        const float4 y = *(const float4*)(p + kbase + 4);
        v[0] = (short)f2bf(x.x); v[1] = (short)f2bf(x.y);
        v[2] = (short)f2bf(x.z); v[3] = (short)f2bf(x.w);
        v[4] = (short)f2bf(y.x); v[5] = (short)f2bf(y.y);
        v[6] = (short)f2bf(y.z); v[7] = (short)f2bf(y.w);
    } else {
#pragma unroll
        for (int i = 0; i < 8; ++i) {
            const int k = kbase + i;
            const float f = (ok && k < Ktot) ? p[k] : 0.f;
            v[i] = (short)f2bf(f);
        }
    }
    return v;
}

// Fused attention: per-b block (1024 threads = 16 waves).
// e[l] = sum_d a_i[b,d,l] w_a[d] + h.w_h + bias ; alpha = softmax(e)
// beta = sigmoid(h.gate_w + gb) ; z[b,d] = beta * sum_l alpha[l] a_i[b,d,l]
__global__ __launch_bounds__(1024) void att_fused(
    const float* __restrict__ a_i, const float* __restrict__ h,
    const float* __restrict__ f_att_w, const float* __restrict__ f_att_b,
    const float* __restrict__ gate_w, const float* __restrict__ gate_b,
    float* __restrict__ alpha_out, float* __restrict__ z)
{
    const int b = blockIdx.x;
    const int t = threadIdx.x;          // 0..1023
    const int w = t >> 6, lane = t & 63;
    __shared__ float pe[16][200];
    __shared__ float red[1024];
    __shared__ float red2[1024];
    __shared__ float al[200];
    __shared__ float sc[2];

    // h dot products (N=1024, one elem per thread)
    const float hv = h[(size_t)b * NN + t];
    red[t]  = hv * f_att_w[DD + t];
    red2[t] = hv * gate_w[t];
    __syncthreads();
    for (int s = 512; s > 0; s >>= 1) {
        if (t < s) { red[t] += red[t + s]; red2[t] += red2[t + s]; }
        __syncthreads();
    }
    if (t == 0) { sc[0] = red[0]; sc[1] = red2[0]; }
    __syncthreads();

    const float* abase = a_i + (size_t)b * DD * LL;

    // phase 1: partial e. wave w covers d in [w*32, w*32+32)
    float e4[4] = {0.f, 0.f, 0.f, 0.f};
    if (lane < 49) {
#pragma unroll 4
        for (int i = 0; i < 32; ++i) {
            const int d = w * 32 + i;
            const float4 a4 = *(const float4*)(abase + (size_t)d * LL + lane * 4);
            const float wa = f_att_w[d];
            e4[0] += a4.x * wa; e4[1] += a4.y * wa;
            e4[2] += a4.z * wa; e4[3] += a4.w * wa;
        }
        *(float4*)&pe[w][lane * 4] = *(const float4*)e4;
    }
    __syncthreads();

    // reduce over waves + softmax over l
    float e = -3.4e38f;
    if (t < LL) {
        e = f_att_b[0] + sc[0];
#pragma unroll
        for (int ww = 0; ww < 16; ++ww) e += pe[ww][t];
    }
    red[t] = e;
    __syncthreads();
    for (int s = 512; s > 0; s >>= 1) {
        if (t < s) red[t] = fmaxf(red[t], red[t + s]);
        __syncthreads();
    }
    const float mx = red[0];
    __syncthreads();
    const float ex = (t < LL) ? expf(e - mx) : 0.f;
    red[t] = ex;
    __syncthreads();
    for (int s = 512; s > 0; s >>= 1) {
        if (t < s) red[t] += red[t + s];
        __syncthreads();
    }
    const float inv = 1.f / red[0];
    if (t < LL) {
        const float a = ex * inv;
        al[t] = a;
        alpha_out[(size_t)b * LL + t] = a;
    }
    __syncthreads();
    const float beta = 1.f / (1.f + expf(-(sc[1] + gate_b[0])));

    // phase 2: z. wave w handles d = i*16 + w (a_i[b] hot in L2/L3)
    for (int i = 0; i < 32; ++i) {
        const int d = i * 16 + w;
        float s = 0.f;
        if (lane < 49) {
            const float4 a4 = *(const float4*)(abase + (size_t)d * LL + lane * 4);
            const float4 av = *(const float4*)&al[lane * 4];
            s = a4.x * av.x + a4.y * av.y + a4.z * av.z + a4.w * av.w;
        }
#pragma unroll
        for (int off = 32; off > 0; off >>= 1) s += __shfl_down(s, off, 64);
        if (lane == 0) z[(size_t)b * DD + d] = beta * s;
    }
}

// TN GEMM via bf16 MFMA: C[r,c] = sum_k A[r,k] * Bw[c,k], fp32 in/out.
// 64x64 tile, BK=64, 256 threads (4 waves as 2x2 of 32x32), split-K via
// blockIdx.z writing partials at C + z*(gridDim.x*64)*ldc.
// LDS rows padded to 72 shorts (144B): uniform bank spread for ds_read_b128.
__global__ __launch_bounds__(256) void gemm_tn_mfma(
    const float* __restrict__ A, int lda,
    const float* __restrict__ Bw, int ldb,
    float* __restrict__ C, int ldc,
    int Ncols, int Ktot, int ktPerSplit,
    const float* __restrict__ bias)
{
    __shared__ __align__(16) short As[2][64][72];
    __shared__ __align__(16) short Bs[2][64][72];
    const int t = threadIdx.x;
    const int row0 = blockIdx.x * 64;
    const int col0 = blockIdx.y * 64;
    const int ktTot = (Ktot + 63) >> 6;
    const int kt0 = blockIdx.z * ktPerSplit;
    const int nk = min(ktTot, kt0 + ktPerSplit) - kt0;

    // staging coords: thread t loads 16 k-contiguous elems of row sr
    const int sr = t >> 2;
    const int sk = (t & 3) << 4;
    const float* aP = A + (size_t)(row0 + sr) * lda;
    const int bc = col0 + sr;
    const bool bok = (bc < Ncols);
    const float* bP = Bw + (size_t)(bok ? bc : 0) * ldb;

    // fragment coords
    const int l = t & 63, w = t >> 6;
    const int wrow = (w >> 1) * 32, wcol = (w & 1) * 32;
    const int lr = l & 15, g = l >> 4, g8 = g * 8;

    f32x4 acc[2][2] = {};

    int k0 = kt0 << 6;
    short8v sa0 = stage8(aP, true, k0 + sk, Ktot);
    short8v sa1 = stage8(aP, true, k0 + sk + 8, Ktot);
    short8v sb0 = stage8(bP, bok, k0 + sk, Ktot);
    short8v sb1 = stage8(bP, bok, k0 + sk + 8, Ktot);
    *(short8v*)&As[0][sr][sk] = sa0;
    *(short8v*)&As[0][sr][sk + 8] = sa1;
    *(short8v*)&Bs[0][sr][sk] = sb0;
    *(short8v*)&Bs[0][sr][sk + 8] = sb1;
    __syncthreads();

    int cur = 0;
    for (int kt = 0; kt < nk; ++kt) {
        const bool more = (kt + 1 < nk);
        if (more) {
            k0 = (kt0 + kt + 1) << 6;
            sa0 = stage8(aP, true, k0 + sk, Ktot);
            sa1 = stage8(aP, true, k0 + sk + 8, Ktot);
            sb0 = stage8(bP, bok, k0 + sk, Ktot);
            sb1 = stage8(bP, bok, k0 + sk + 8, Ktot);
        }
#pragma unroll
        for (int ks = 0; ks < 2; ++ks) {
            const int ko = ks * 32 + g8;
            short8v a0 = *(const short8v*)&As[cur][wrow + lr][ko];
            short8v a1 = *(const short8v*)&As[cur][wrow + 16 + lr][ko];
            short8v b0 = *(const short8v*)&Bs[cur][wcol + lr][ko];
            short8v b1 = *(const short8v*)&Bs[cur][wcol + 16 + lr][ko];
            acc[0][0] = __builtin_amdgcn_mfma_f32_16x16x32_bf16(a0, b0, acc[0][0], 0, 0, 0);
            acc[0][1] = __builtin_amdgcn_mfma_f32_16x16x32_bf16(a0, b1, acc[0][1], 0, 0, 0);
            acc[1][0] = __builtin_amdgcn_mfma_f32_16x16x32_bf16(a1, b0, acc[1][0], 0, 0, 0);
            acc[1][1] = __builtin_amdgcn_mfma_f32_16x16x32_bf16(a1, b1, acc[1][1], 0, 0, 0);
        }
        if (more) {
            *(short8v*)&As[cur ^ 1][sr][sk] = sa0;
            *(short8v*)&As[cur ^ 1][sr][sk + 8] = sa1;
            *(short8v*)&Bs[cur ^ 1][sr][sk] = sb0;
            *(short8v*)&Bs[cur ^ 1][sr][sk + 8] = sb1;
        }
        __syncthreads();
        cur ^= 1;
    }

    float* Cp = C + (size_t)blockIdx.z * ((size_t)gridDim.x * 64) * ldc;
#pragma unroll
    for (int m = 0; m < 2; ++m)
#pragma unroll
        for (int n = 0; n < 2; ++n)
#pragma unroll
            for (int j = 0; j < 4; ++j) {
                const int r = row0 + wrow + m * 16 + g * 4 + j;
                const int c = col0 + wcol + n * 16 + lr;
                if (c < Ncols) {
                    float v = acc[m][n][j];
                    if (bias) v += bias[c];
                    Cp[(size_t)r * ldc + c] = v;
                }
            }
}

// x = [w_emb | h | z] with w_emb = sum of nEmb partials + E_b
__global__ __launch_bounds__(256) void build_x(
    const float* __restrict__ embp, int nEmb, const float* __restrict__ E_b,
    const float* __restrict__ h, const float* __restrict__ z,
    float* __restrict__ x)
{
    const int idx = blockIdx.x * 256 + threadIdx.x;   // < B*2048
    const int b = idx >> 11, j = idx & 2047;
    float v;
    if (j < 512) {
        v = E_b[j];
        for (int s = 0; s < nEmb; ++s) v += embp[(size_t)s * BB * 512 + (size_t)b * 512 + j];
    } else if (j < 1536) {
        v = h[(size_t)b * NN + (j - 512)];
    } else {
        v = z[(size_t)b * DD + (j - 1536)];
    }
    x[idx] = v;
}

__global__ __launch_bounds__(256) void lstm_cell(
    const float* __restrict__ ihp, int nIh,
    const float* __restrict__ hhp, int nHh,
    const float* __restrict__ b_ih, const float* __restrict__ b_hh,
    const float* __restrict__ c_prev, float* __restrict__ hn, float* __restrict__ cn)
{
    const int idx = blockIdx.x * 256 + threadIdx.x;   // < B*1024
    const int b = idx >> 10, n = idx & 1023;
    float g[4];
#pragma unroll
    for (int gi = 0; gi < 4; ++gi) {
        const int col = gi * 1024 + n;
        const size_t o = (size_t)b * 4096 + col;
        float v = b_ih[col] + b_hh[col];
        for (int s = 0; s < nIh; ++s) v += ihp[(size_t)s * BB * 4096 + o];
        for (int s = 0; s < nHh; ++s) v += hhp[(size_t)s * BB * 4096 + o];
        g[gi] = v;
    }
    const float si = 1.f / (1.f + expf(-g[0]));
    const float sf = 1.f / (1.f + expf(-g[1]));
    const float so = 1.f / (1.f + expf(-g[3]));
    const float tg = tanhf(g[2]);
    const float c = c_prev[idx];
    const float cnv = sf * c + si * tg;
    const float hnv = so * tanhf(cnv);
    cn[idx] = cnv;
    hn[idx] = hnv;
}

// deep = w_emb + sum(lh partials) + sum(lz partials) + Lh_b + Lz_b
__global__ __launch_bounds__(256) void build_deep(
    const float* __restrict__ x, const float* __restrict__ lhp, int nLh,
    const float* __restrict__ lzp, int nLz, const float* __restrict__ Lh_b,
    const float* __restrict__ Lz_b, float* __restrict__ deep)
{
    const int idx = blockIdx.x * 256 + threadIdx.x;   // < B*512
    const int b = idx >> 9, j = idx & 511;
    float v = x[(size_t)b * 2048 + j] + Lh_b[j] + Lz_b[j];
    for (int s = 0; s < nLh; ++s) v += lhp[(size_t)s * BB * 512 + idx];
    for (int s = 0; s < nLz; ++s) v += lzp[(size_t)s * BB * 512 + idx];
    deep[idx] = v;
}

extern "C" void kernel_launch(void* const* d_in, const int* in_sizes, int n_in,
                              void* d_out, int out_size, void* d_ws, size_t ws_size,
                              hipStream_t stream)
{
    const float* a_i     = (const float*)d_in[0];
    const float* inp     = (const float*)d_in[1];
    const float* hn_prev = (const float*)d_in[2];
    const float* cn_prev = (const float*)d_in[3];
    const float* f_att_w = (const float*)d_in[4];
    const float* f_att_b = (const float*)d_in[5];
    const float* gate_w  = (const float*)d_in[6];
    const float* gate_b  = (const float*)d_in[7];
    const float* E_w     = (const float*)d_in[8];
    const float* E_b     = (const float*)d_in[9];
    const float* W_ih    = (const float*)d_in[10];
    const float* W_hh    = (const float*)d_in[11];
    const float* b_ih    = (const float*)d_in[12];
    const float* b_hh    = (const float*)d_in[13];
    const float* Lh_w    = (const float*)d_in[14];
    const float* Lh_b    = (const float*)d_in[15];
    const float* Lz_w    = (const float*)d_in[16];
    const float* Lz_b    = (const float*)d_in[17];
    const float* Lo_w    = (const float*)d_in[18];
    const float* Lo_b    = (const float*)d_in[19];

    float* out = (float*)d_out;
    float* ws  = (float*)d_ws;

    // ---- workspace layout ----
    const size_t off_z    = 0;          // B*D    = 131072
    const size_t off_x    = 131072;     // B*2048 = 524288
    const size_t off_deep = 655360;     // B*M    = 131072
    const size_t small_end = 786432;

    const size_t avail = ws_size / sizeof(float);
    // big: R1 = max(32 emb, 4 ih, 8 lh slices) = 4194304
    //      R2 = max(4 hh, 4 lz slices)         = 4194304
    const bool big = (avail >= (size_t)9175040);
    const int embS = big ? 32 : 8;
    const int ihS  = big ? 4 : 2;
    const int hhS  = big ? 4 : 2;
    const int lhS  = big ? 8 : 4;
    const int lzS  = big ? 4 : 2;
    const size_t r1sz = big ? (size_t)4194304 : (size_t)2097152;
    const size_t off_r1 = small_end;
    const size_t off_r2 = small_end + r1sz;

    float* EMBP = ws + off_r1;   // embS * B*512
    float* IHP  = ws + off_r1;   // ihS  * B*4096  (after build_x)
    float* LHP  = ws + off_r1;   // lhS  * B*512   (after lstm_cell)
    float* HHP  = ws + off_r2;   // hhS  * B*4096
    float* LZP  = ws + off_r2;   // lzS  * B*512   (after lstm_cell)

    // w_emb = inp @ E_w.T : ktTot = 157 (BK=64)
    gemm_tn_mfma<<<dim3(4, 8, embS), 256, 0, stream>>>(inp, KK, E_w, KK,
                                                       EMBP, MM, MM, KK,
                                                       (157 + embS - 1) / embS, nullptr);
    // fused attention
    att_fused<<<BB, 1024, 0, stream>>>(a_i, hn_prev, f_att_w, f_att_b,
                                       gate_w, gate_b, out + OUT_AL, ws + off_z);
    // h @ W_hh.T (independent of attention)
    gemm_tn_mfma<<<dim3(4, 64, hhS), 256, 0, stream>>>(hn_prev, NN, W_hh, NN,
                                                       HHP, 4096, 4096, NN, 16 / hhS, nullptr);
    build_x<<<BB * 2048 / 256, 256, 0, stream>>>(EMBP, embS, E_b, hn_prev,
                                                 ws + off_z, ws + off_x);
    // gates = x @ W_ih.T
    gemm_tn_mfma<<<dim3(4, 64, ihS), 256, 0, stream>>>(ws + off_x, 2048, W_ih, 2048,
                                                       IHP, 4096, 4096, 2048, 32 / ihS, nullptr);
    lstm_cell<<<BB * NN / 256, 256, 0, stream>>>(IHP, ihS, HHP, hhS, b_ih, b_hh,
                                                 cn_prev, out + OUT_HN, out + OUT_CN);

    // deep_out = w_emb + hn @ Lh_w.T + Lh_b + z @ Lz_w.T + Lz_b
    gemm_tn_mfma<<<dim3(4, 8, lhS), 256, 0, stream>>>(out + OUT_HN, NN, Lh_w, NN,
                                                      LHP, MM, MM, NN, 16 / lhS, nullptr);
    gemm_tn_mfma<<<dim3(4, 8, lzS), 256, 0, stream>>>(ws + off_z, DD, Lz_w, DD,
                                                      LZP, MM, MM, DD, 8 / lzS, nullptr);
    build_deep<<<BB * MM / 256, 256, 0, stream>>>(ws + off_x, LHP, lhS, LZP, lzS,
                                                  Lh_b, Lz_b, ws + off_deep);

    // p_yt = deep @ Lo_w.T + Lo_b  (Ncols=10000, guarded)
    gemm_tn_mfma<<<dim3(4, 157, 1), 256, 0, stream>>>(ws + off_deep, MM, Lo_w, MM,
                                                      out + OUT_PY, KK, KK, MM, 8, Lo_b);
}

// Round 5
// 175.282 us; speedup vs baseline: 2.1654x; 1.0417x over previous
//
#include <hip/hip_runtime.h>
#include <hip/hip_bf16.h>
#include <math.h>

// Problem constants
#define BB 256
#define DD 512
#define LL 196
#define NN 1024
#define MM 512
#define KK 10000

// ---- output layout (float offsets) ----
#define OUT_PY 0
#define OUT_HN ((size_t)2560000)
#define OUT_CN ((size_t)2822144)
#define OUT_AL ((size_t)3084288)

typedef __attribute__((ext_vector_type(8))) short short8v;
typedef __attribute__((ext_vector_type(4))) float f32x4;

__device__ __forceinline__ unsigned short f2bf(float f) {
    unsigned int u = __builtin_bit_cast(unsigned int, f);
    u += 0x7fffu + ((u >> 16) & 1u);            // round-to-nearest-even
    return (unsigned short)(u >> 16);
}

// load 8 k-contiguous floats (guarded) -> bf16x8
__device__ __forceinline__ short8v stage8(const float* __restrict__ p, bool ok,
                                          int kbase, int Ktot) {
    short8v v;
    if (ok && (kbase + 7 < Ktot)) {
        const float4 x = *(const float4*)(p + kbase);
        const float4 y = *(const float4*)(p + kbase + 4);
        v[0] = (short)f2bf(x.x); v[1] = (short)f2bf(x.y);
        v[2] = (short)f2bf(x.z); v[3] = (short)f2bf(x.w);
        v[4] = (short)f2bf(y.x); v[5] = (short)f2bf(y.y);
        v[6] = (short)f2bf(y.z); v[7] = (short)f2bf(y.w);
    } else {
#pragma unroll
        for (int i = 0; i < 8; ++i) {
            const int k = kbase + i;
            const float f = (ok && k < Ktot) ? p[k] : 0.f;
            v[i] = (short)f2bf(f);
        }
    }
    return v;
}

// Fused attention, per-b block (1024 threads = 16 waves), 8-deep load staging.
__global__ __launch_bounds__(1024) void att_fused(
    const float* __restrict__ a_i, const float* __restrict__ h,
    const float* __restrict__ f_att_w, const float* __restrict__ f_att_b,
    const float* __restrict__ gate_w, const float* __restrict__ gate_b,
    float* __restrict__ alpha_out, float* __restrict__ z)
{
    const int b = blockIdx.x;
    const int t = threadIdx.x;
    const int w = t >> 6, lane = t & 63;
    __shared__ float pe[16][200];
    __shared__ float red[32];
    __shared__ float red2[16];
    __shared__ __align__(16) float al[200];
    __shared__ float wsh[DD];
    __shared__ float sc[2];

    if (t < DD) wsh[t] = f_att_w[t];

    // h dot products: wave shuffle-reduce, then cross-wave by thread 0
    const float hv = h[(size_t)b * NN + t];
    float hd = hv * f_att_w[DD + t];
    float gd = hv * gate_w[t];
#pragma unroll
    for (int off = 32; off > 0; off >>= 1) {
        hd += __shfl_down(hd, off, 64);
        gd += __shfl_down(gd, off, 64);
    }
    if (lane == 0) { red[w] = hd; red2[w] = gd; }
    __syncthreads();
    if (t == 0) {
        float s0 = 0.f, s1 = 0.f;
#pragma unroll
        for (int ww = 0; ww < 16; ++ww) { s0 += red[ww]; s1 += red2[ww]; }
        sc[0] = s0; sc[1] = s1;
    }

    const float* abase = a_i + (size_t)b * DD * LL;
    const float* rp = abase + (size_t)(w * 32) * LL + lane * 4;

    // phase 1: partial e; wave w covers d in [w*32, w*32+32), 8 rows in flight
    float e4[4] = {0.f, 0.f, 0.f, 0.f};
    if (lane < 49) {
        for (int base = 0; base < 32; base += 8) {
            float4 buf[8];
#pragma unroll
            for (int j = 0; j < 8; ++j)
                buf[j] = *(const float4*)(rp + (size_t)(base + j) * LL);
#pragma unroll
            for (int j = 0; j < 8; ++j) {
                const float wa = wsh[w * 32 + base + j];
                e4[0] += buf[j].x * wa; e4[1] += buf[j].y * wa;
                e4[2] += buf[j].z * wa; e4[3] += buf[j].w * wa;
            }
        }
        *(float4*)&pe[w][lane * 4] = *(const float4*)e4;
    }
    __syncthreads();

    // e gather (t<196 spans waves 0..3) + softmax via wave shuffles
    float e = -3.4e38f;
    if (t < LL) {
        e = f_att_b[0] + sc[0];
#pragma unroll
        for (int ww = 0; ww < 16; ++ww) e += pe[ww][t];
    }
    float m = e;
#pragma unroll
    for (int off = 32; off > 0; off >>= 1) m = fmaxf(m, __shfl_down(m, off, 64));
    if (w < 4 && lane == 0) red[w] = m;
    __syncthreads();
    const float mx = fmaxf(fmaxf(red[0], red[1]), fmaxf(red[2], red[3]));
    const float ex = (t < LL) ? expf(e - mx) : 0.f;
    float s = ex;
#pragma unroll
    for (int off = 32; off > 0; off >>= 1) s += __shfl_down(s, off, 64);
    if (w < 4 && lane == 0) red[16 + w] = s;
    __syncthreads();
    const float inv = 1.f / (red[16] + red[17] + red[18] + red[19]);
    if (t < LL) {
        const float a = ex * inv;
        al[t] = a;
        alpha_out[(size_t)b * LL + t] = a;
    }
    __syncthreads();

    // phase 2: z over same rows (L2/L3-hot), 8 rows in flight
    const float beta = 1.f / (1.f + expf(-(sc[1] + gate_b[0])));
    float4 av = make_float4(0.f, 0.f, 0.f, 0.f);
    if (lane < 49) av = *(const float4*)&al[lane * 4];
    for (int base = 0; base < 32; base += 8) {
        float4 buf[8];
        if (lane < 49) {
#pragma unroll
            for (int j = 0; j < 8; ++j)
                buf[j] = *(const float4*)(rp + (size_t)(base + j) * LL);
        }
#pragma unroll
        for (int j = 0; j < 8; ++j) {
            float sj = (lane < 49) ? (buf[j].x * av.x + buf[j].y * av.y +
                                      buf[j].z * av.z + buf[j].w * av.w) : 0.f;
#pragma unroll
            for (int off = 32; off > 0; off >>= 1) sj += __shfl_down(sj, off, 64);
            if (lane == 0) z[(size_t)b * DD + w * 32 + base + j] = beta * sj;
        }
    }
}

// Dual-source TN GEMM via bf16 MFMA:
//   C[r,c] = sum_k A1[r,k]*B1[c,k] (kt1n BK-tiles) + sum_k A2[r,k]*B2[c,k] (kt2n)
// fp32 in/out, 64x64 tile, BK=64, 256 threads, split-K via blockIdx.z writing
// partials at C + z*(gridDim.x*64)*ldc. Pass A2=nullptr, kt2n=0 for single.
__global__ __launch_bounds__(256) void gemm_tn_dual(
    const float* __restrict__ A1, int lda1, const float* __restrict__ B1, int ldb1,
    int kt1n, int K1,
    const float* __restrict__ A2, int lda2, const float* __restrict__ B2, int ldb2,
    int kt2n, int K2,
    float* __restrict__ C, int ldc, int Ncols, int ktPerSplit,
    const float* __restrict__ bias)
{
    __shared__ __align__(16) short As[2][64][72];
    __shared__ __align__(16) short Bs[2][64][72];
    const int t = threadIdx.x;
    const int row0 = blockIdx.x * 64;
    const int col0 = blockIdx.y * 64;
    const int ktTot = kt1n + kt2n;
    const int kt0 = blockIdx.z * ktPerSplit;
    const int nk = min(ktTot, kt0 + ktPerSplit) - kt0;

    const int sr = t >> 2;
    const int sk = (t & 3) << 4;
    const int bc = col0 + sr;
    const bool bok = (bc < Ncols);
    const float* aP1 = A1 + (size_t)(row0 + sr) * lda1;
    const float* bP1 = B1 + (size_t)(bok ? bc : 0) * ldb1;
    const float* aP2 = A2 ? (A2 + (size_t)(row0 + sr) * lda2) : aP1;
    const float* bP2 = A2 ? (B2 + (size_t)(bok ? bc : 0) * ldb2) : bP1;

    const int l = t & 63, w = t >> 6;
    const int wrow = (w >> 1) * 32, wcol = (w & 1) * 32;
    const int lr = l & 15, g = l >> 4, g8 = g * 8;

    f32x4 acc[2][2] = {};

    short8v sa0, sa1, sb0, sb1;
    {
        const int ktg = kt0;
        const float* aR; const float* bR; int kk, Kt;
        if (ktg < kt1n) { aR = aP1; bR = bP1; kk = (ktg << 6) + sk; Kt = K1; }
        else            { aR = aP2; bR = bP2; kk = ((ktg - kt1n) << 6) + sk; Kt = K2; }
        sa0 = stage8(aR, true, kk, Kt);  sa1 = stage8(aR, true, kk + 8, Kt);
        sb0 = stage8(bR, bok,  kk, Kt);  sb1 = stage8(bR, bok,  kk + 8, Kt);
    }
    *(short8v*)&As[0][sr][sk] = sa0; *(short8v*)&As[0][sr][sk + 8] = sa1;
    *(short8v*)&Bs[0][sr][sk] = sb0; *(short8v*)&Bs[0][sr][sk + 8] = sb1;
    __syncthreads();

    int cur = 0;
    for (int kt = 0; kt < nk; ++kt) {
        const bool more = (kt + 1 < nk);
        if (more) {
            const int ktg = kt0 + kt + 1;
            const float* aR; const float* bR; int kk, Kt;
            if (ktg < kt1n) { aR = aP1; bR = bP1; kk = (ktg << 6) + sk; Kt = K1; }
            else            { aR = aP2; bR = bP2; kk = ((ktg - kt1n) << 6) + sk; Kt = K2; }
            sa0 = stage8(aR, true, kk, Kt);  sa1 = stage8(aR, true, kk + 8, Kt);
            sb0 = stage8(bR, bok,  kk, Kt);  sb1 = stage8(bR, bok,  kk + 8, Kt);
        }
#pragma unroll
        for (int ks = 0; ks < 2; ++ks) {
            const int ko = ks * 32 + g8;
            short8v a0 = *(const short8v*)&As[cur][wrow + lr][ko];
            short8v a1 = *(const short8v*)&As[cur][wrow + 16 + lr][ko];
            short8v b0 = *(const short8v*)&Bs[cur][wcol + lr][ko];
            short8v b1 = *(const short8v*)&Bs[cur][wcol + 16 + lr][ko];
            acc[0][0] = __builtin_amdgcn_mfma_f32_16x16x32_bf16(a0, b0, acc[0][0], 0, 0, 0);
            acc[0][1] = __builtin_amdgcn_mfma_f32_16x16x32_bf16(a0, b1, acc[0][1], 0, 0, 0);
            acc[1][0] = __builtin_amdgcn_mfma_f32_16x16x32_bf16(a1, b0, acc[1][0], 0, 0, 0);
            acc[1][1] = __builtin_amdgcn_mfma_f32_16x16x32_bf16(a1, b1, acc[1][1], 0, 0, 0);
        }
        if (more) {
            *(short8v*)&As[cur ^ 1][sr][sk] = sa0;
            *(short8v*)&As[cur ^ 1][sr][sk + 8] = sa1;
            *(short8v*)&Bs[cur ^ 1][sr][sk] = sb0;
            *(short8v*)&Bs[cur ^ 1][sr][sk + 8] = sb1;
        }
        __syncthreads();
        cur ^= 1;
    }

    float* Cp = C + (size_t)blockIdx.z * ((size_t)gridDim.x * 64) * ldc;
#pragma unroll
    for (int m = 0; m < 2; ++m)
#pragma unroll
        for (int n = 0; n < 2; ++n)
#pragma unroll
            for (int j = 0; j < 4; ++j) {
                const int r = row0 + wrow + m * 16 + g * 4 + j;
                const int c = col0 + wcol + n * 16 + lr;
                if (c < Ncols) {
                    float v = acc[m][n][j];
                    if (bias) v += bias[c];
                    Cp[(size_t)r * ldc + c] = v;
                }
            }
}

// x = [w_emb | h | z] with w_emb = sum of nEmb partials + E_b
__global__ __launch_bounds__(256) void build_x(
    const float* __restrict__ embp, int nEmb, const float* __restrict__ E_b,
    const float* __restrict__ h, const float* __restrict__ z,
    float* __restrict__ x)
{
    const int idx = blockIdx.x * 256 + threadIdx.x;   // < B*2048
    const int b = idx >> 11, j = idx & 2047;
    float v;
    if (j < 512) {
        v = E_b[j];
        for (int s = 0; s < nEmb; ++s) v += embp[(size_t)s * BB * 512 + (size_t)b * 512 + j];
    } else if (j < 1536) {
        v = h[(size_t)b * NN + (j - 512)];
    } else {
        v = z[(size_t)b * DD + (j - 1536)];
    }
    x[idx] = v;
}

__global__ __launch_bounds__(256) void lstm_cell(
    const float* __restrict__ gatesp, int nG,
    const float* __restrict__ b_ih, const float* __restrict__ b_hh,
    const float* __restrict__ c_prev, float* __restrict__ hn, float* __restrict__ cn)
{
    const int idx = blockIdx.x * 256 + threadIdx.x;   // < B*1024
    const int b = idx >> 10, n = idx & 1023;
    float g[4];
#pragma unroll
    for (int gi = 0; gi < 4; ++gi) {
        const int col = gi * 1024 + n;
        const size_t o = (size_t)b * 4096 + col;
        float v = b_ih[col] + b_hh[col];
        for (int s = 0; s < nG; ++s) v += gatesp[(size_t)s * BB * 4096 + o];
        g[gi] = v;
    }
    const float si = 1.f / (1.f + expf(-g[0]));
    const float sf = 1.f / (1.f + expf(-g[1]));
    const float so = 1.f / (1.f + expf(-g[3]));
    const float tg = tanhf(g[2]);
    const float c = c_prev[idx];
    const float cnv = sf * c + si * tg;
    const float hnv = so * tanhf(cnv);
    cn[idx] = cnv;
    hn[idx] = hnv;
}

// deep = w_emb + sum(lh partials) + sum(lz partials) + Lh_b + Lz_b
__global__ __launch_bounds__(256) void build_deep(
    const float* __restrict__ x, const float* __restrict__ lhp, int nLh,
    const float* __restrict__ lzp, int nLz, const float* __restrict__ Lh_b,
    const float* __restrict__ Lz_b, float* __restrict__ deep)
{
    const int idx = blockIdx.x * 256 + threadIdx.x;   // < B*512
    const int b = idx >> 9, j = idx & 511;
    float v = x[(size_t)b * 2048 + j] + Lh_b[j] + Lz_b[j];
    for (int s = 0; s < nLh; ++s) v += lhp[(size_t)s * BB * 512 + idx];
    for (int s = 0; s < nLz; ++s) v += lzp[(size_t)s * BB * 512 + idx];
    deep[idx] = v;
}

extern "C" void kernel_launch(void* const* d_in, const int* in_sizes, int n_in,
                              void* d_out, int out_size, void* d_ws, size_t ws_size,
                              hipStream_t stream)
{
    const float* a_i     = (const float*)d_in[0];
    const float* inp     = (const float*)d_in[1];
    const float* hn_prev = (const float*)d_in[2];
    const float* cn_prev = (const float*)d_in[3];
    const float* f_att_w = (const float*)d_in[4];
    const float* f_att_b = (const float*)d_in[5];
    const float* gate_w  = (const float*)d_in[6];
    const float* gate_b  = (const float*)d_in[7];
    const float* E_w     = (const float*)d_in[8];
    const float* E_b     = (const float*)d_in[9];
    const float* W_ih    = (const float*)d_in[10];
    const float* W_hh    = (const float*)d_in[11];
    const float* b_ih    = (const float*)d_in[12];
    const float* b_hh    = (const float*)d_in[13];
    const float* Lh_w    = (const float*)d_in[14];
    const float* Lh_b    = (const float*)d_in[15];
    const float* Lz_w    = (const float*)d_in[16];
    const float* Lz_b    = (const float*)d_in[17];
    const float* Lo_w    = (const float*)d_in[18];
    const float* Lo_b    = (const float*)d_in[19];

    float* out = (float*)d_out;
    float* ws  = (float*)d_ws;

    // ---- workspace layout ----
    const size_t off_z    = 0;          // B*D    = 131072
    const size_t off_x    = 131072;     // B*2048 = 524288
    const size_t off_deep = 655360;     // B*M    = 131072
    const size_t small_end = 786432;

    const size_t avail = ws_size / sizeof(float);
    // big: R1 = max(32 emb, 8 gates, 16 lh slices) = 8388608 ; R2 = 8 lz = 1048576
    const bool big = (avail >= (size_t)(786432 + 8388608 + 1048576));
    const int embS = big ? 32 : 8;
    const int gS   = big ? 8 : 2;
    const int lhS  = big ? 16 : 4;
    const int lzS  = big ? 8 : 2;
    const size_t r1sz = big ? (size_t)8388608 : (size_t)2097152;
    const size_t off_r1 = small_end;
    const size_t off_r2 = small_end + r1sz;

    float* EMBP   = ws + off_r1;   // embS * B*512
    float* GATESP = ws + off_r1;   // gS   * B*4096  (after build_x)
    float* LHP    = ws + off_r1;   // lhS  * B*512   (after lstm_cell)
    float* LZP    = ws + off_r2;   // lzS  * B*512

    // w_emb = inp @ E_w.T : ktTot = 157 (BK=64)
    gemm_tn_dual<<<dim3(4, 8, embS), 256, 0, stream>>>(
        inp, KK, E_w, KK, 157, KK,
        nullptr, 0, nullptr, 0, 0, 0,
        EMBP, MM, MM, (157 + embS - 1) / embS, nullptr);

    // fused attention
    att_fused<<<BB, 1024, 0, stream>>>(a_i, hn_prev, f_att_w, f_att_b,
                                       gate_w, gate_b, out + OUT_AL, ws + off_z);

    build_x<<<BB * 2048 / 256, 256, 0, stream>>>(EMBP, embS, E_b, hn_prev,
                                                 ws + off_z, ws + off_x);

    // gates = x @ W_ih.T (32 tiles) + h @ W_hh.T (16 tiles), fused dual-source
    gemm_tn_dual<<<dim3(4, 64, gS), 256, 0, stream>>>(
        ws + off_x, 2048, W_ih, 2048, 32, 2048,
        hn_prev, NN, W_hh, NN, 16, NN,
        GATESP, 4096, 4096, 48 / gS, nullptr);

    lstm_cell<<<BB * NN / 256, 256, 0, stream>>>(GATESP, gS, b_ih, b_hh,
                                                 cn_prev, out + OUT_HN, out + OUT_CN);

    // deep_out = w_emb + hn @ Lh_w.T + Lh_b + z @ Lz_w.T + Lz_b
    gemm_tn_dual<<<dim3(4, 8, lhS), 256, 0, stream>>>(
        out + OUT_HN, NN, Lh_w, NN, 16, NN,
        nullptr, 0, nullptr, 0, 0, 0,
        LHP, MM, MM, 16 / lhS, nullptr);
    gemm_tn_dual<<<dim3(4, 8, lzS), 256, 0, stream>>>(
        ws + off_z, DD, Lz_w, DD, 8, DD,
        nullptr, 0, nullptr, 0, 0, 0,
        LZP, MM, MM, 8 / lzS, nullptr);
    build_deep<<<BB * MM / 256, 256, 0, stream>>>(ws + off_x, LHP, lhS, LZP, lzS,
                                                  Lh_b, Lz_b, ws + off_deep);

    // p_yt = deep @ Lo_w.T + Lo_b  (Ncols=10000, guarded)
    gemm_tn_dual<<<dim3(4, 157, 1), 256, 0, stream>>>(
        ws + off_deep, MM, Lo_w, MM, 8, MM,
        nullptr, 0, nullptr, 0, 0, 0,
        out + OUT_PY, KK, KK, 8, Lo_b);
}

// Round 6
// 168.053 us; speedup vs baseline: 2.2586x; 1.0430x over previous
//
#include <hip/hip_runtime.h>
#include <hip/hip_bf16.h>
#include <math.h>

// Problem constants
#define BB 256
#define DD 512
#define LL 196
#define NN 1024
#define MM 512
#define KK 10000

// ---- output layout (float offsets) ----
#define OUT_PY 0
#define OUT_HN ((size_t)2560000)
#define OUT_CN ((size_t)2822144)
#define OUT_AL ((size_t)3084288)

typedef __attribute__((ext_vector_type(8))) short short8v;
typedef __attribute__((ext_vector_type(4))) float f32x4;

__device__ __forceinline__ unsigned short f2bf(float f) {
    unsigned int u = __builtin_bit_cast(unsigned int, f);
    u += 0x7fffu + ((u >> 16) & 1u);            // round-to-nearest-even
    return (unsigned short)(u >> 16);
}

// load 8 k-contiguous floats (guarded) -> bf16x8
__device__ __forceinline__ short8v stage8(const float* __restrict__ p, bool ok,
                                          int kbase, int Ktot) {
    short8v v;
    if (ok && (kbase + 7 < Ktot)) {
        const float4 x = *(const float4*)(p + kbase);
        const float4 y = *(const float4*)(p + kbase + 4);
        v[0] = (short)f2bf(x.x); v[1] = (short)f2bf(x.y);
        v[2] = (short)f2bf(x.z); v[3] = (short)f2bf(x.w);
        v[4] = (short)f2bf(y.x); v[5] = (short)f2bf(y.y);
        v[6] = (short)f2bf(y.z); v[7] = (short)f2bf(y.w);
    } else {
#pragma unroll
        for (int i = 0; i < 8; ++i) {
            const int k = kbase + i;
            const float f = (ok && k < Ktot) ? p[k] : 0.f;
            v[i] = (short)f2bf(f);
        }
    }
    return v;
}

// pe[b][ch][l] = sum_{d in 64-chunk ch} a_i[b,d,l] * w_a[d]
// grid (B, 8) = 2048 blocks -> 8 blocks/CU, full occupancy, deep ILP.
__global__ __launch_bounds__(256) void att_e_partial(
    const float* __restrict__ a_i, const float* __restrict__ f_att_w,
    float* __restrict__ pe)
{
    const int b = blockIdx.x, ch = blockIdx.y;
    const int l = threadIdx.x;
    if (l >= LL) return;
    const float* ap = a_i + ((size_t)b * DD + ch * 64) * LL + l;
    const float* wp = f_att_w + ch * 64;
    float s = 0.f;
#pragma unroll 16
    for (int d = 0; d < 64; ++d) s += ap[(size_t)d * LL] * wp[d];
    pe[((size_t)b * 8 + ch) * LL + l] = s;
}

// per-b: hdot=h.w_h, gdot=h.gate_w, e=sum(pe)+hdot+bias, softmax->alpha;
// beta = sigmoid(gdot+gb)
__global__ __launch_bounds__(256) void att_softmax(
    const float* __restrict__ pe, const float* __restrict__ h,
    const float* __restrict__ f_att_w, const float* __restrict__ f_att_b,
    const float* __restrict__ gate_w, const float* __restrict__ gate_b,
    float* __restrict__ alpha_out, float* __restrict__ beta)
{
    const int b = blockIdx.x;
    const int t = threadIdx.x;
    __shared__ float red[256];
    __shared__ float red2[256];

    const float4 h4 = *(const float4*)(h + (size_t)b * NN + t * 4);
    const float4 w4 = *(const float4*)(f_att_w + DD + t * 4);
    const float4 g4 = *(const float4*)(gate_w + t * 4);
    float hd = h4.x * w4.x + h4.y * w4.y + h4.z * w4.z + h4.w * w4.w;
    float gd = h4.x * g4.x + h4.y * g4.y + h4.z * g4.z + h4.w * g4.w;
    red[t] = hd; red2[t] = gd;
    __syncthreads();
    for (int s = 128; s > 0; s >>= 1) {
        if (t < s) { red[t] += red[t + s]; red2[t] += red2[t + s]; }
        __syncthreads();
    }
    const float hdot = red[0];
    const float gdot = red2[0];
    __syncthreads();

    float e = -3.4e38f;
    if (t < LL) {
        const float* p = pe + (size_t)b * 8 * LL + t;
        e = hdot + f_att_b[0];
#pragma unroll
        for (int ch = 0; ch < 8; ++ch) e += p[ch * LL];
    }
    red[t] = e;
    __syncthreads();
    for (int s = 128; s > 0; s >>= 1) {
        if (t < s) red[t] = fmaxf(red[t], red[t + s]);
        __syncthreads();
    }
    const float mx = red[0];
    __syncthreads();
    const float ex = (t < LL) ? expf(e - mx) : 0.f;
    red[t] = ex;
    __syncthreads();
    for (int s = 128; s > 0; s >>= 1) {
        if (t < s) red[t] += red[t + s];
        __syncthreads();
    }
    const float inv = 1.f / red[0];
    if (t < LL) alpha_out[(size_t)b * LL + t] = ex * inv;
    if (t == 0) beta[b] = 1.f / (1.f + expf(-(gdot + gate_b[0])));
}

// z[b,d] = beta[b] * sum_l alpha[b,l] * a_i[b,d,l] ; one wave per d.
// Second a_i pass: L3-resident (a_i = 103 MB < 256 MB Infinity Cache).
__global__ __launch_bounds__(256) void att_z(
    const float* __restrict__ a_i, const float* __restrict__ alpha,
    const float* __restrict__ beta, float* __restrict__ z)
{
    const int b = blockIdx.x;
    const int wave = threadIdx.x >> 6, lane = threadIdx.x & 63;
    const int d = blockIdx.y * 4 + wave;
    const float* ap = a_i + ((size_t)b * DD + d) * LL;
    const float* alp = alpha + (size_t)b * LL;
    float s = 0.f;
#pragma unroll
    for (int i = 0; i < 4; ++i) {
        const int l = lane + i * 64;
        if (l < LL) s += ap[l] * alp[l];
    }
#pragma unroll
    for (int off = 32; off > 0; off >>= 1) s += __shfl_down(s, off, 64);
    if (lane == 0) z[(size_t)b * DD + d] = beta[b] * s;
}

// Dual-source TN GEMM via bf16 MFMA:
//   C[r,c] = sum_k A1[r,k]*B1[c,k] (kt1n BK-tiles) + sum_k A2[r,k]*B2[c,k] (kt2n)
// fp32 in/out, 64x64 tile, BK=64, 256 threads, split-K via blockIdx.z writing
// partials at C + z*(gridDim.x*64)*ldc. Pass A2=nullptr, kt2n=0 for single.
__global__ __launch_bounds__(256) void gemm_tn_dual(
    const float* __restrict__ A1, int lda1, const float* __restrict__ B1, int ldb1,
    int kt1n, int K1,
    const float* __restrict__ A2, int lda2, const float* __restrict__ B2, int ldb2,
    int kt2n, int K2,
    float* __restrict__ C, int ldc, int Ncols, int ktPerSplit,
    const float* __restrict__ bias)
{
    __shared__ __align__(16) short As[2][64][72];
    __shared__ __align__(16) short Bs[2][64][72];
    const int t = threadIdx.x;
    const int row0 = blockIdx.x * 64;
    const int col0 = blockIdx.y * 64;
    const int ktTot = kt1n + kt2n;
    const int kt0 = blockIdx.z * ktPerSplit;
    const int nk = min(ktTot, kt0 + ktPerSplit) - kt0;

    const int sr = t >> 2;
    const int sk = (t & 3) << 4;
    const int bc = col0 + sr;
    const bool bok = (bc < Ncols);
    const float* aP1 = A1 + (size_t)(row0 + sr) * lda1;
    const float* bP1 = B1 + (size_t)(bok ? bc : 0) * ldb1;
    const float* aP2 = A2 ? (A2 + (size_t)(row0 + sr) * lda2) : aP1;
    const float* bP2 = A2 ? (B2 + (size_t)(bok ? bc : 0) * ldb2) : bP1;

    const int l = t & 63, w = t >> 6;
    const int wrow = (w >> 1) * 32, wcol = (w & 1) * 32;
    const int lr = l & 15, g = l >> 4, g8 = g * 8;

    f32x4 acc[2][2] = {};

    short8v sa0, sa1, sb0, sb1;
    {
        const int ktg = kt0;
        const float* aR; const float* bR; int kk, Kt;
        if (ktg < kt1n) { aR = aP1; bR = bP1; kk = (ktg << 6) + sk; Kt = K1; }
        else            { aR = aP2; bR = bP2; kk = ((ktg - kt1n) << 6) + sk; Kt = K2; }
        sa0 = stage8(aR, true, kk, Kt);  sa1 = stage8(aR, true, kk + 8, Kt);
        sb0 = stage8(bR, bok,  kk, Kt);  sb1 = stage8(bR, bok,  kk + 8, Kt);
    }
    *(short8v*)&As[0][sr][sk] = sa0; *(short8v*)&As[0][sr][sk + 8] = sa1;
    *(short8v*)&Bs[0][sr][sk] = sb0; *(short8v*)&Bs[0][sr][sk + 8] = sb1;
    __syncthreads();

    int cur = 0;
    for (int kt = 0; kt < nk; ++kt) {
        const bool more = (kt + 1 < nk);
        if (more) {
            const int ktg = kt0 + kt + 1;
            const float* aR; const float* bR; int kk, Kt;
            if (ktg < kt1n) { aR = aP1; bR = bP1; kk = (ktg << 6) + sk; Kt = K1; }
            else            { aR = aP2; bR = bP2; kk = ((ktg - kt1n) << 6) + sk; Kt = K2; }
            sa0 = stage8(aR, true, kk, Kt);  sa1 = stage8(aR, true, kk + 8, Kt);
            sb0 = stage8(bR, bok,  kk, Kt);  sb1 = stage8(bR, bok,  kk + 8, Kt);
        }
#pragma unroll
        for (int ks = 0; ks < 2; ++ks) {
            const int ko = ks * 32 + g8;
            short8v a0 = *(const short8v*)&As[cur][wrow + lr][ko];
            short8v a1 = *(const short8v*)&As[cur][wrow + 16 + lr][ko];
            short8v b0 = *(const short8v*)&Bs[cur][wcol + lr][ko];
            short8v b1 = *(const short8v*)&Bs[cur][wcol + 16 + lr][ko];
            acc[0][0] = __builtin_amdgcn_mfma_f32_16x16x32_bf16(a0, b0, acc[0][0], 0, 0, 0);
            acc[0][1] = __builtin_amdgcn_mfma_f32_16x16x32_bf16(a0, b1, acc[0][1], 0, 0, 0);
            acc[1][0] = __builtin_amdgcn_mfma_f32_16x16x32_bf16(a1, b0, acc[1][0], 0, 0, 0);
            acc[1][1] = __builtin_amdgcn_mfma_f32_16x16x32_bf16(a1, b1, acc[1][1], 0, 0, 0);
        }
        if (more) {
            *(short8v*)&As[cur ^ 1][sr][sk] = sa0;
            *(short8v*)&As[cur ^ 1][sr][sk + 8] = sa1;
            *(short8v*)&Bs[cur ^ 1][sr][sk] = sb0;
            *(short8v*)&Bs[cur ^ 1][sr][sk + 8] = sb1;
        }
        __syncthreads();
        cur ^= 1;
    }

    float* Cp = C + (size_t)blockIdx.z * ((size_t)gridDim.x * 64) * ldc;
#pragma unroll
    for (int m = 0; m < 2; ++m)
#pragma unroll
        for (int n = 0; n < 2; ++n)
#pragma unroll
            for (int j = 0; j < 4; ++j) {
                const int r = row0 + wrow + m * 16 + g * 4 + j;
                const int c = col0 + wcol + n * 16 + lr;
                if (c < Ncols) {
                    float v = acc[m][n][j];
                    if (bias) v += bias[c];
                    Cp[(size_t)r * ldc + c] = v;
                }
            }
}

// x = [w_emb | h | z] with w_emb = sum of nEmb partials + E_b
__global__ __launch_bounds__(256) void build_x(
    const float* __restrict__ embp, int nEmb, const float* __restrict__ E_b,
    const float* __restrict__ h, const float* __restrict__ z,
    float* __restrict__ x)
{
    const int idx = blockIdx.x * 256 + threadIdx.x;   // < B*2048
    const int b = idx >> 11, j = idx & 2047;
    float v;
    if (j < 512) {
        v = E_b[j];
        for (int s = 0; s < nEmb; ++s) v += embp[(size_t)s * BB * 512 + (size_t)b * 512 + j];
    } else if (j < 1536) {
        v = h[(size_t)b * NN + (j - 512)];
    } else {
        v = z[(size_t)b * DD + (j - 1536)];
    }
    x[idx] = v;
}

__global__ __launch_bounds__(256) void lstm_cell(
    const float* __restrict__ gatesp, int nG,
    const float* __restrict__ b_ih, const float* __restrict__ b_hh,
    const float* __restrict__ c_prev, float* __restrict__ hn, float* __restrict__ cn)
{
    const int idx = blockIdx.x * 256 + threadIdx.x;   // < B*1024
    const int b = idx >> 10, n = idx & 1023;
    float g[4];
#pragma unroll
    for (int gi = 0; gi < 4; ++gi) {
        const int col = gi * 1024 + n;
        const size_t o = (size_t)b * 4096 + col;
        float v = b_ih[col] + b_hh[col];
        for (int s = 0; s < nG; ++s) v += gatesp[(size_t)s * BB * 4096 + o];
        g[gi] = v;
    }
    const float si = 1.f / (1.f + expf(-g[0]));
    const float sf = 1.f / (1.f + expf(-g[1]));
    const float so = 1.f / (1.f + expf(-g[3]));
    const float tg = tanhf(g[2]);
    const float c = c_prev[idx];
    const float cnv = sf * c + si * tg;
    const float hnv = so * tanhf(cnv);
    cn[idx] = cnv;
    hn[idx] = hnv;
}

// deep = w_emb + sum(dp partials) + Lh_b + Lz_b
__global__ __launch_bounds__(256) void build_deep(
    const float* __restrict__ x, const float* __restrict__ dp, int nD,
    const float* __restrict__ Lh_b, const float* __restrict__ Lz_b,
    float* __restrict__ deep)
{
    const int idx = blockIdx.x * 256 + threadIdx.x;   // < B*512
    const int b = idx >> 9, j = idx & 511;
    float v = x[(size_t)b * 2048 + j] + Lh_b[j] + Lz_b[j];
    for (int s = 0; s < nD; ++s) v += dp[(size_t)s * BB * 512 + idx];
    deep[idx] = v;
}

extern "C" void kernel_launch(void* const* d_in, const int* in_sizes, int n_in,
                              void* d_out, int out_size, void* d_ws, size_t ws_size,
                              hipStream_t stream)
{
    const float* a_i     = (const float*)d_in[0];
    const float* inp     = (const float*)d_in[1];
    const float* hn_prev = (const float*)d_in[2];
    const float* cn_prev = (const float*)d_in[3];
    const float* f_att_w = (const float*)d_in[4];
    const float* f_att_b = (const float*)d_in[5];
    const float* gate_w  = (const float*)d_in[6];
    const float* gate_b  = (const float*)d_in[7];
    const float* E_w     = (const float*)d_in[8];
    const float* E_b     = (const float*)d_in[9];
    const float* W_ih    = (const float*)d_in[10];
    const float* W_hh    = (const float*)d_in[11];
    const float* b_ih    = (const float*)d_in[12];
    const float* b_hh    = (const float*)d_in[13];
    const float* Lh_w    = (const float*)d_in[14];
    const float* Lh_b    = (const float*)d_in[15];
    const float* Lz_w    = (const float*)d_in[16];
    const float* Lz_b    = (const float*)d_in[17];
    const float* Lo_w    = (const float*)d_in[18];
    const float* Lo_b    = (const float*)d_in[19];

    float* out = (float*)d_out;
    float* ws  = (float*)d_ws;

    // ---- workspace layout (float offsets) ----
    const size_t off_pe   = 0;          // B*8*196 = 401408
    const size_t off_beta = 401408;     // 256
    const size_t off_z    = 401664;     // B*D    = 131072
    const size_t off_x    = 532736;     // B*2048 = 524288
    const size_t off_deep = 1057024;    // B*M    = 131072
    const size_t small_end = 1188096;

    const size_t avail = ws_size / sizeof(float);
    // R1 = max(16 emb, 4 gates, 12 deep slices) = 4 * B*4096 = 4194304 floats
    const bool big = (avail >= small_end + (size_t)4194304);
    const int embS = big ? 16 : 4;
    const int gS   = big ? 4 : 2;
    const int dS   = big ? 12 : 4;
    const size_t off_r1 = small_end;

    float* EMBP   = ws + off_r1;   // embS * B*512
    float* GATESP = ws + off_r1;   // gS   * B*4096  (after build_x)
    float* DP     = ws + off_r1;   // dS   * B*512   (after lstm_cell)

    // attention (a_i stays L3-resident between the two passes)
    att_e_partial<<<dim3(BB, 8), 256, 0, stream>>>(a_i, f_att_w, ws + off_pe);
    att_softmax<<<BB, 256, 0, stream>>>(ws + off_pe, hn_prev, f_att_w, f_att_b,
                                        gate_w, gate_b, out + OUT_AL, ws + off_beta);
    att_z<<<dim3(BB, DD / 4), 256, 0, stream>>>(a_i, out + OUT_AL, ws + off_beta,
                                                ws + off_z);

    // w_emb = inp @ E_w.T : ktTot = 157 (BK=64)
    gemm_tn_dual<<<dim3(4, 8, embS), 256, 0, stream>>>(
        inp, KK, E_w, KK, 157, KK,
        nullptr, 0, nullptr, 0, 0, 0,
        EMBP, MM, MM, (157 + embS - 1) / embS, nullptr);

    build_x<<<BB * 2048 / 256, 256, 0, stream>>>(EMBP, embS, E_b, hn_prev,
                                                 ws + off_z, ws + off_x);

    // gates = x @ W_ih.T (32 tiles) + h @ W_hh.T (16 tiles), dual-source
    gemm_tn_dual<<<dim3(4, 64, gS), 256, 0, stream>>>(
        ws + off_x, 2048, W_ih, 2048, 32, 2048,
        hn_prev, NN, W_hh, NN, 16, NN,
        GATESP, 4096, 4096, 48 / gS, nullptr);

    lstm_cell<<<BB * NN / 256, 256, 0, stream>>>(GATESP, gS, b_ih, b_hh,
                                                 cn_prev, out + OUT_HN, out + OUT_CN);

    // deep partials = hn @ Lh_w.T (16 tiles) + z @ Lz_w.T (8 tiles), dual-source
    gemm_tn_dual<<<dim3(4, 8, dS), 256, 0, stream>>>(
        out + OUT_HN, NN, Lh_w, NN, 16, NN,
        ws + off_z, DD, Lz_w, DD, 8, DD,
        DP, MM, MM, 24 / dS, nullptr);

    build_deep<<<BB * MM / 256, 256, 0, stream>>>(ws + off_x, DP, dS,
                                                  Lh_b, Lz_b, ws + off_deep);

    // p_yt = deep @ Lo_w.T + Lo_b  (Ncols=10000, guarded)
    gemm_tn_dual<<<dim3(4, 157, 1), 256, 0, stream>>>(
        ws + off_deep, MM, Lo_w, MM, 8, MM,
        nullptr, 0, nullptr, 0, 0, 0,
        out + OUT_PY, KK, KK, 8, Lo_b);
}

// Round 7
// 156.868 us; speedup vs baseline: 2.4196x; 1.0713x over previous
//
#include <hip/hip_runtime.h>
#include <hip/hip_bf16.h>
#include <math.h>

// Problem constants
#define BB 256
#define DD 512
#define LL 196
#define NN 1024
#define MM 512
#define KK 10000

// ---- output layout (float offsets) ----
#define OUT_PY 0
#define OUT_HN ((size_t)2560000)
#define OUT_CN ((size_t)2822144)
#define OUT_AL ((size_t)3084288)

// ---- workspace layout (float offsets), no aliasing (ws is ~390 MB) ----
#define OFF_PE    ((size_t)0)         // B*8*196 = 401408
#define OFF_BETA  ((size_t)401408)    // 256
#define OFF_Z     ((size_t)401664)    // B*512   = 131072
#define OFF_EMB   ((size_t)532736)    // B*512   = 131072
#define OFF_DEEP  ((size_t)663808)    // B*512   = 131072
#define OFF_EMBP  ((size_t)794880)    // 16 * B*512  = 2097152
#define OFF_GATESP ((size_t)2892032)  // 6 * B*4096  = 6291456
#define OFF_DP    ((size_t)9183488)   // 24 * B*512  = 3145728
// end 12329216 floats = 49.3 MB

typedef __attribute__((ext_vector_type(8))) short short8v;
typedef __attribute__((ext_vector_type(4))) float f32x4;

__device__ __forceinline__ short bfs(float f) {
    __hip_bfloat16 h = __float2bfloat16(f);   // RNE, hw cvt (m240)
    return *reinterpret_cast<short*>(&h);
}

// load 8 k-contiguous floats (guarded) -> bf16x8
__device__ __forceinline__ short8v stage8(const float* __restrict__ p, bool ok,
                                          int kbase, int Ktot) {
    short8v v;
    if (ok && (kbase + 7 < Ktot)) {
        const float4 x = *(const float4*)(p + kbase);
        const float4 y = *(const float4*)(p + kbase + 4);
        v[0] = bfs(x.x); v[1] = bfs(x.y); v[2] = bfs(x.z); v[3] = bfs(x.w);
        v[4] = bfs(y.x); v[5] = bfs(y.y); v[6] = bfs(y.z); v[7] = bfs(y.w);
    } else {
#pragma unroll
        for (int i = 0; i < 8; ++i) {
            const int k = kbase + i;
            v[i] = bfs((ok && k < Ktot) ? p[k] : 0.f);
        }
    }
    return v;
}

struct GSrc { const float* A; int lda; const float* B; int ldb; int ktn; int K; };

// Dual-source TN GEMM body (bf16 MFMA), 64x64 tile, BK=64, 256 threads.
// C[r,c] = sum over src1 then src2 K-tiles of A[r,k]*B[c,k].
// Split-K slice bz writes at C + bz*(rowBlocks*64)*ldc.
__device__ __forceinline__ void gemm_body(
    const int bx, const int by, const int bz, const int rowBlocks,
    const GSrc s1, const GSrc s2,
    float* __restrict__ C, const int ldc, const int Ncols,
    const int ktPerSplit, const float* __restrict__ bias,
    short (*As)[64][72], short (*Bs)[64][72])
{
    const int t = threadIdx.x;
    const int row0 = bx * 64;
    const int col0 = by * 64;
    const int ktTot = s1.ktn + s2.ktn;
    const int kt0 = bz * ktPerSplit;
    const int nk = min(ktTot, kt0 + ktPerSplit) - kt0;

    const int sr = t >> 2;
    const int sk = (t & 3) << 4;
    const int bc = col0 + sr;
    const bool bok = (bc < Ncols);
    const float* aP1 = s1.A + (size_t)(row0 + sr) * s1.lda;
    const float* bP1 = s1.B + (size_t)(bok ? bc : 0) * s1.ldb;
    const float* aP2 = s2.A ? (s2.A + (size_t)(row0 + sr) * s2.lda) : aP1;
    const float* bP2 = s2.A ? (s2.B + (size_t)(bok ? bc : 0) * s2.ldb) : bP1;

    const int l = t & 63, w = t >> 6;
    const int wrow = (w >> 1) * 32, wcol = (w & 1) * 32;
    const int lr = l & 15, g = l >> 4, g8 = g * 8;

    f32x4 acc[2][2] = {};

    short8v sa0, sa1, sb0, sb1;
    {
        const int ktg = kt0;
        const float* aR; const float* bR; int kk, Kt;
        if (ktg < s1.ktn) { aR = aP1; bR = bP1; kk = (ktg << 6) + sk; Kt = s1.K; }
        else              { aR = aP2; bR = bP2; kk = ((ktg - s1.ktn) << 6) + sk; Kt = s2.K; }
        sa0 = stage8(aR, true, kk, Kt);  sa1 = stage8(aR, true, kk + 8, Kt);
        sb0 = stage8(bR, bok,  kk, Kt);  sb1 = stage8(bR, bok,  kk + 8, Kt);
    }
    *(short8v*)&As[0][sr][sk] = sa0; *(short8v*)&As[0][sr][sk + 8] = sa1;
    *(short8v*)&Bs[0][sr][sk] = sb0; *(short8v*)&Bs[0][sr][sk + 8] = sb1;
    __syncthreads();

    int cur = 0;
    for (int kt = 0; kt < nk; ++kt) {
        const bool more = (kt + 1 < nk);
        if (more) {
            const int ktg = kt0 + kt + 1;
            const float* aR; const float* bR; int kk, Kt;
            if (ktg < s1.ktn) { aR = aP1; bR = bP1; kk = (ktg << 6) + sk; Kt = s1.K; }
            else              { aR = aP2; bR = bP2; kk = ((ktg - s1.ktn) << 6) + sk; Kt = s2.K; }
            sa0 = stage8(aR, true, kk, Kt);  sa1 = stage8(aR, true, kk + 8, Kt);
            sb0 = stage8(bR, bok,  kk, Kt);  sb1 = stage8(bR, bok,  kk + 8, Kt);
        }
#pragma unroll
        for (int ks = 0; ks < 2; ++ks) {
            const int ko = ks * 32 + g8;
            short8v a0 = *(const short8v*)&As[cur][wrow + lr][ko];
            short8v a1 = *(const short8v*)&As[cur][wrow + 16 + lr][ko];
            short8v b0 = *(const short8v*)&Bs[cur][wcol + lr][ko];
            short8v b1 = *(const short8v*)&Bs[cur][wcol + 16 + lr][ko];
            acc[0][0] = __builtin_amdgcn_mfma_f32_16x16x32_bf16(a0, b0, acc[0][0], 0, 0, 0);
            acc[0][1] = __builtin_amdgcn_mfma_f32_16x16x32_bf16(a0, b1, acc[0][1], 0, 0, 0);
            acc[1][0] = __builtin_amdgcn_mfma_f32_16x16x32_bf16(a1, b0, acc[1][0], 0, 0, 0);
            acc[1][1] = __builtin_amdgcn_mfma_f32_16x16x32_bf16(a1, b1, acc[1][1], 0, 0, 0);
        }
        if (more) {
            *(short8v*)&As[cur ^ 1][sr][sk] = sa0;
            *(short8v*)&As[cur ^ 1][sr][sk + 8] = sa1;
            *(short8v*)&Bs[cur ^ 1][sr][sk] = sb0;
            *(short8v*)&Bs[cur ^ 1][sr][sk + 8] = sb1;
        }
        __syncthreads();
        cur ^= 1;
    }

    float* Cp = C + (size_t)bz * ((size_t)rowBlocks * 64) * ldc;
#pragma unroll
    for (int m = 0; m < 2; ++m)
#pragma unroll
        for (int n = 0; n < 2; ++n)
#pragma unroll
            for (int j = 0; j < 4; ++j) {
                const int r = row0 + wrow + m * 16 + g * 4 + j;
                const int c = col0 + wcol + n * 16 + lr;
                if (c < Ncols) {
                    float v = acc[m][n][j];
                    if (bias) v += bias[c];
                    Cp[(size_t)r * ldc + c] = v;
                }
            }
}

// ---- P1: att_e_partial (2048 blocks) || emb GEMM (512 blocks) ----
__global__ __launch_bounds__(256) void p1_atte_emb(
    const float* __restrict__ a_i, const float* __restrict__ f_att_w,
    float* __restrict__ pe,
    const float* __restrict__ inp, const float* __restrict__ E_w,
    float* __restrict__ embp)
{
    __shared__ __align__(16) short As[2][64][72];
    __shared__ __align__(16) short Bs[2][64][72];
    const int bid = blockIdx.x;
    if (bid < 2048) {
        const int b = bid >> 3, ch = bid & 7;
        const int l = threadIdx.x;
        if (l >= LL) return;
        const float* ap = a_i + ((size_t)b * DD + ch * 64) * LL + l;
        const float* wp = f_att_w + ch * 64;
        float s = 0.f;
#pragma unroll 16
        for (int d = 0; d < 64; ++d) s += ap[(size_t)d * LL] * wp[d];
        pe[((size_t)b * 8 + ch) * LL + l] = s;
    } else {
        const int i = bid - 2048;                     // 512 = 4*8*16
        GSrc s1 = {inp, KK, E_w, KK, 157, KK};
        GSrc s2 = {nullptr, 0, nullptr, 0, 0, 0};
        gemm_body(i & 3, (i >> 2) & 7, i >> 5, 4, s1, s2,
                  embp, MM, MM, 10, nullptr, As, Bs);
    }
}

// ---- P2: att_softmax (256 blocks) || emb-partial reduce (512 blocks) ----
__global__ __launch_bounds__(256) void p2_softmax_embred(
    const float* __restrict__ pe, const float* __restrict__ h,
    const float* __restrict__ f_att_w, const float* __restrict__ f_att_b,
    const float* __restrict__ gate_w, const float* __restrict__ gate_b,
    float* __restrict__ alpha_out, float* __restrict__ beta,
    const float* __restrict__ embp, const float* __restrict__ E_b,
    float* __restrict__ emb)
{
    const int bid = blockIdx.x;
    const int t = threadIdx.x;
    if (bid < 256) {
        const int b = bid;
        __shared__ float red[256];
        __shared__ float red2[256];
        const float4 h4 = *(const float4*)(h + (size_t)b * NN + t * 4);
        const float4 w4 = *(const float4*)(f_att_w + DD + t * 4);
        const float4 g4 = *(const float4*)(gate_w + t * 4);
        float hd = h4.x * w4.x + h4.y * w4.y + h4.z * w4.z + h4.w * w4.w;
        float gd = h4.x * g4.x + h4.y * g4.y + h4.z * g4.z + h4.w * g4.w;
        red[t] = hd; red2[t] = gd;
        __syncthreads();
        for (int s = 128; s > 0; s >>= 1) {
            if (t < s) { red[t] += red[t + s]; red2[t] += red2[t + s]; }
            __syncthreads();
        }
        const float hdot = red[0];
        const float gdot = red2[0];
        __syncthreads();
        float e = -3.4e38f;
        if (t < LL) {
            const float* p = pe + (size_t)b * 8 * LL + t;
            e = hdot + f_att_b[0];
#pragma unroll
            for (int ch = 0; ch < 8; ++ch) e += p[ch * LL];
        }
        red[t] = e;
        __syncthreads();
        for (int s = 128; s > 0; s >>= 1) {
            if (t < s) red[t] = fmaxf(red[t], red[t + s]);
            __syncthreads();
        }
        const float mx = red[0];
        __syncthreads();
        const float ex = (t < LL) ? expf(e - mx) : 0.f;
        red[t] = ex;
        __syncthreads();
        for (int s = 128; s > 0; s >>= 1) {
            if (t < s) red[t] += red[t + s];
            __syncthreads();
        }
        const float inv = 1.f / red[0];
        if (t < LL) alpha_out[(size_t)b * LL + t] = ex * inv;
        if (t == 0) beta[b] = 1.f / (1.f + expf(-(gdot + gate_b[0])));
    } else {
        const int idx = (bid - 256) * 256 + t;        // < B*512
        const int j = idx & 511;
        float v = E_b[j];
#pragma unroll
        for (int s = 0; s < 16; ++s) v += embp[(size_t)s * (BB * 512) + idx];
        emb[idx] = v;
    }
}

// ---- P3: att_z (8192 blocks) || gates_h GEMM (1024 blocks) ----
__global__ __launch_bounds__(256) void p3_attz_gatesh(
    const float* __restrict__ a_i, const float* __restrict__ alpha,
    const float* __restrict__ beta, float* __restrict__ z,
    const float* __restrict__ h, const float* __restrict__ W_ih,
    const float* __restrict__ W_hh, float* __restrict__ gatesp)
{
    __shared__ __align__(16) short As[2][64][72];
    __shared__ __align__(16) short Bs[2][64][72];
    const int bid = blockIdx.x;
    if (bid < 8192) {
        const int b = bid >> 5, chunk = bid & 31;
        const int wave = threadIdx.x >> 6, lane = threadIdx.x & 63;
        const float* alp = alpha + (size_t)b * LL;
#pragma unroll
        for (int i = 0; i < 4; ++i) {
            const int d = chunk * 16 + wave * 4 + i;
            const float* ap = a_i + ((size_t)b * DD + d) * LL;
            float s = 0.f;
#pragma unroll
            for (int q = 0; q < 4; ++q) {
                const int lidx = lane + q * 64;
                if (lidx < LL) s += ap[lidx] * alp[lidx];
            }
#pragma unroll
            for (int off = 32; off > 0; off >>= 1) s += __shfl_down(s, off, 64);
            if (lane == 0) z[(size_t)b * DD + d] = beta[b] * s;
        }
    } else {
        const int i = bid - 8192;                     // 1024 = 4*64*4
        GSrc s1 = {h, NN, W_ih + 512, 2048, 16, NN};
        GSrc s2 = {h, NN, W_hh, NN, 16, NN};
        gemm_body(i & 3, (i >> 2) & 63, i >> 8, 4, s1, s2,
                  gatesp, 4096, 4096, 8, nullptr, As, Bs);
    }
}

// ---- P4: gates_ez GEMM (512 blocks) || lz GEMM (256 blocks) ----
__global__ __launch_bounds__(256) void p4_gatesez_lz(
    const float* __restrict__ emb, const float* __restrict__ z,
    const float* __restrict__ W_ih, float* __restrict__ gatesp_hi,
    const float* __restrict__ Lz_w, float* __restrict__ dp)
{
    __shared__ __align__(16) short As[2][64][72];
    __shared__ __align__(16) short Bs[2][64][72];
    const int bid = blockIdx.x;
    if (bid < 512) {                                  // 4*64*2
        GSrc s1 = {emb, MM, W_ih, 2048, 8, MM};
        GSrc s2 = {z, DD, W_ih + 1536, 2048, 8, DD};
        gemm_body(bid & 3, (bid >> 2) & 63, bid >> 8, 4, s1, s2,
                  gatesp_hi, 4096, 4096, 8, nullptr, As, Bs);
    } else {
        const int i = bid - 512;                      // 256 = 4*8*8
        GSrc s1 = {z, DD, Lz_w, DD, 8, DD};
        GSrc s2 = {nullptr, 0, nullptr, 0, 0, 0};
        gemm_body(i & 3, (i >> 2) & 7, i >> 5, 4, s1, s2,
                  dp, MM, MM, 1, nullptr, As, Bs);
    }
}

// ---- P5: lstm cell (1024 blocks) ----
__global__ __launch_bounds__(256) void p5_lstm(
    const float* __restrict__ gatesp,
    const float* __restrict__ b_ih, const float* __restrict__ b_hh,
    const float* __restrict__ c_prev, float* __restrict__ hn, float* __restrict__ cn)
{
    const int idx = blockIdx.x * 256 + threadIdx.x;   // < B*1024
    const int b = idx >> 10, n = idx & 1023;
    float g[4];
#pragma unroll
    for (int gi = 0; gi < 4; ++gi) {
        const int col = gi * 1024 + n;
        const size_t o = (size_t)b * 4096 + col;
        float v = b_ih[col] + b_hh[col];
#pragma unroll
        for (int s = 0; s < 6; ++s) v += gatesp[(size_t)s * (BB * 4096) + o];
        g[gi] = v;
    }
    const float si = 1.f / (1.f + expf(-g[0]));
    const float sf = 1.f / (1.f + expf(-g[1]));
    const float so = 1.f / (1.f + expf(-g[3]));
    const float tg = tanhf(g[2]);
    const float c = c_prev[idx];
    const float cnv = sf * c + si * tg;
    const float hnv = so * tanhf(cnv);
    cn[idx] = cnv;
    hn[idx] = hnv;
}

// ---- P6: lh GEMM (512 blocks) ----
__global__ __launch_bounds__(256) void p6_lh(
    const float* __restrict__ hn, const float* __restrict__ Lh_w,
    float* __restrict__ dp_hi)
{
    __shared__ __align__(16) short As[2][64][72];
    __shared__ __align__(16) short Bs[2][64][72];
    const int bid = blockIdx.x;                       // 512 = 4*8*16
    GSrc s1 = {hn, NN, Lh_w, NN, 16, NN};
    GSrc s2 = {nullptr, 0, nullptr, 0, 0, 0};
    gemm_body(bid & 3, (bid >> 2) & 7, bid >> 5, 4, s1, s2,
              dp_hi, MM, MM, 1, nullptr, As, Bs);
}

// ---- P7: build deep (512 blocks) ----
__global__ __launch_bounds__(256) void p7_deep(
    const float* __restrict__ emb, const float* __restrict__ dp,
    const float* __restrict__ Lh_b, const float* __restrict__ Lz_b,
    float* __restrict__ deep)
{
    const int idx = blockIdx.x * 256 + threadIdx.x;   // < B*512
    const int j = idx & 511;
    float v = emb[idx] + Lh_b[j] + Lz_b[j];
#pragma unroll
    for (int s = 0; s < 24; ++s) v += dp[(size_t)s * (BB * 512) + idx];
    deep[idx] = v;
}

// ---- P8: p_yt GEMM (628 blocks) ----
__global__ __launch_bounds__(256) void p8_pyt(
    const float* __restrict__ deep, const float* __restrict__ Lo_w,
    const float* __restrict__ Lo_b, float* __restrict__ out)
{
    __shared__ __align__(16) short As[2][64][72];
    __shared__ __align__(16) short Bs[2][64][72];
    const int bid = blockIdx.x;                       // 628 = 4*157
    GSrc s1 = {deep, MM, Lo_w, MM, 8, MM};
    GSrc s2 = {nullptr, 0, nullptr, 0, 0, 0};
    gemm_body(bid & 3, bid >> 2, 0, 4, s1, s2,
              out, KK, KK, 8, Lo_b, As, Bs);
}

extern "C" void kernel_launch(void* const* d_in, const int* in_sizes, int n_in,
                              void* d_out, int out_size, void* d_ws, size_t ws_size,
                              hipStream_t stream)
{
    const float* a_i     = (const float*)d_in[0];
    const float* inp     = (const float*)d_in[1];
    const float* hn_prev = (const float*)d_in[2];
    const float* cn_prev = (const float*)d_in[3];
    const float* f_att_w = (const float*)d_in[4];
    const float* f_att_b = (const float*)d_in[5];
    const float* gate_w  = (const float*)d_in[6];
    const float* gate_b  = (const float*)d_in[7];
    const float* E_w     = (const float*)d_in[8];
    const float* E_b     = (const float*)d_in[9];
    const float* W_ih    = (const float*)d_in[10];
    const float* W_hh    = (const float*)d_in[11];
    const float* b_ih    = (const float*)d_in[12];
    const float* b_hh    = (const float*)d_in[13];
    const float* Lh_w    = (const float*)d_in[14];
    const float* Lh_b    = (const float*)d_in[15];
    const float* Lz_w    = (const float*)d_in[16];
    const float* Lz_b    = (const float*)d_in[17];
    const float* Lo_w    = (const float*)d_in[18];
    const float* Lo_b    = (const float*)d_in[19];

    float* out = (float*)d_out;
    float* ws  = (float*)d_ws;

    float* PE     = ws + OFF_PE;
    float* BETA   = ws + OFF_BETA;
    float* Z      = ws + OFF_Z;
    float* EMB    = ws + OFF_EMB;
    float* DEEP   = ws + OFF_DEEP;
    float* EMBP   = ws + OFF_EMBP;
    float* GATESP = ws + OFF_GATESP;
    float* DP     = ws + OFF_DP;

    // P1: attention e-partials || emb GEMM (independent, both input-only)
    p1_atte_emb<<<2560, 256, 0, stream>>>(a_i, f_att_w, PE, inp, E_w, EMBP);

    // P2: softmax+beta || emb partial reduce
    p2_softmax_embred<<<768, 256, 0, stream>>>(PE, hn_prev, f_att_w, f_att_b,
                                               gate_w, gate_b, out + OUT_AL, BETA,
                                               EMBP, E_b, EMB);

    // P3: z reduction || gates h-part GEMM (h@W_ih_h + h@W_hh, slices 0..3)
    p3_attz_gatesh<<<9216, 256, 0, stream>>>(a_i, out + OUT_AL, BETA, Z,
                                             hn_prev, W_ih, W_hh, GATESP);

    // P4: gates emb/z-part GEMM (slices 4..5) || z@Lz_w^T (dp slices 0..7)
    p4_gatesez_lz<<<768, 256, 0, stream>>>(EMB, Z, W_ih,
                                           GATESP + (size_t)4 * BB * 4096,
                                           Lz_w, DP);

    // P5: LSTM cell
    p5_lstm<<<1024, 256, 0, stream>>>(GATESP, b_ih, b_hh, cn_prev,
                                      out + OUT_HN, out + OUT_CN);

    // P6: hn@Lh_w^T (dp slices 8..23)
    p6_lh<<<512, 256, 0, stream>>>(out + OUT_HN, Lh_w,
                                   DP + (size_t)8 * BB * 512);

    // P7: deep = emb + sum(dp) + biases
    p7_deep<<<512, 256, 0, stream>>>(EMB, DP, Lh_b, Lz_b, DEEP);

    // P8: p_yt = deep @ Lo_w^T + Lo_b
    p8_pyt<<<628, 256, 0, stream>>>(DEEP, Lo_w, Lo_b, out + OUT_PY);
}